// Round 1
// baseline (1332.007 us; speedup 1.0000x reference)
//
#include <hip/hip_runtime.h>

// ---------------------------------------------------------------------------
// VirusHostCoexistenceModel: 4×GATConv + 2×(Linear+BN+LeakyReLU) + vh@hh^T
// Constants from the reference
#define NV   6000
#define NH   6000
#define DD   1024       // DV == DH == 1024
#define HID  128
#define EV   200000
#define EH   200000
#define EC   32768

typedef __attribute__((ext_vector_type(8))) short bf16x8;
typedef __attribute__((ext_vector_type(4))) float f32x4;

__device__ __forceinline__ unsigned short f2bf(float f){
  unsigned u = __float_as_uint(f);
  u += 0x7FFFu + ((u >> 16) & 1u);        // RNE bf16
  return (unsigned short)(u >> 16);
}
// order-preserving float<->uint encoding for atomicMax on floats
__device__ __forceinline__ unsigned fenc(float x){
  unsigned u = __float_as_uint(x);
  return (u & 0x80000000u) ? ~u : (u | 0x80000000u);
}
__device__ __forceinline__ float fdec(unsigned v){
  return (v & 0x80000000u) ? __uint_as_float(v & 0x7FFFFFFFu) : __uint_as_float(~v);
}

// ------------------------- pack / transpose --------------------------------
__global__ void k_cv(const float* __restrict__ src, unsigned short* __restrict__ dst, int n4){
  int i = blockIdx.x * blockDim.x + threadIdx.x;
  if (i < n4){
    float4 v = reinterpret_cast<const float4*>(src)[i];
    ushort4 o; o.x = f2bf(v.x); o.y = f2bf(v.y); o.z = f2bf(v.z); o.w = f2bf(v.w);
    reinterpret_cast<ushort4*>(dst)[i] = o;
  }
}

// dst[(n+row_off)*1024 + k] = bf16(src[k*Nc + n]); src is [1024, Nc] f32
__global__ void k_tp(const float* __restrict__ src, unsigned short* __restrict__ dst,
                     int Nc, int row_off, int total){
  for (int idx = blockIdx.x * blockDim.x + threadIdx.x; idx < total; idx += gridDim.x * blockDim.x){
    int n = idx >> 10, k = idx & 1023;
    dst[(size_t)(n + row_off) * 1024 + k] = f2bf(src[(size_t)k * Nc + n]);
  }
}

// ------------------------- NT bf16 MFMA GEMM -------------------------------
// C[m,n] = sum_k A[m,k] * B[n,k]   (A:[M,K] bf16 lda, B:[N,K] bf16 ldb)
// If C1o != null: also C1o[idx]=v and C2o[idx]=2v (triple-write epilogue).
__global__ __launch_bounds__(256) void k_gemm_nt(
    const unsigned short* __restrict__ A, const unsigned short* __restrict__ B,
    int M, int N, int K, int lda, int ldb,
    float* __restrict__ C0, float* __restrict__ C1o, float* __restrict__ C2o, int ldc)
{
  const int tid  = threadIdx.x;
  const int lane = tid & 63, w = tid >> 6;
  const int wr = w >> 1, wc = w & 1;
  const int R  = blockIdx.y * 128 + wr * 64;
  const int Cb = blockIdx.x * 128 + wc * 64;
  const int r0 = lane & 15, kg = lane >> 4;

  const unsigned short* pa[4]; const unsigned short* pb[4];
  bool va[4], vb[4];
#pragma unroll
  for (int i = 0; i < 4; i++){
    int row = R + i * 16 + r0;
    va[i] = row < M;
    pa[i] = A + (size_t)(va[i] ? row : 0) * lda + kg * 8;
    int col = Cb + i * 16 + r0;
    vb[i] = col < N;
    pb[i] = B + (size_t)(vb[i] ? col : 0) * ldb + kg * 8;
  }
  const bf16x8 Z8 = {0,0,0,0,0,0,0,0};
  f32x4 acc[4][4];
#pragma unroll
  for (int i = 0; i < 4; i++)
#pragma unroll
    for (int j = 0; j < 4; j++) acc[i][j] = (f32x4){0.f,0.f,0.f,0.f};

  for (int kk = 0; kk < K; kk += 32){
    bf16x8 av[4], bv[4];
#pragma unroll
    for (int i = 0; i < 4; i++){
      bf16x8 ta = *reinterpret_cast<const bf16x8*>(pa[i] + kk);
      bf16x8 tb = *reinterpret_cast<const bf16x8*>(pb[i] + kk);
      av[i] = va[i] ? ta : Z8;
      bv[i] = vb[i] ? tb : Z8;
    }
#pragma unroll
    for (int i = 0; i < 4; i++)
#pragma unroll
      for (int j = 0; j < 4; j++)
        acc[i][j] = __builtin_amdgcn_mfma_f32_16x16x32_bf16(av[i], bv[j], acc[i][j], 0, 0, 0);
  }

  const int cn = lane & 15, rq = (lane >> 4) * 4;
#pragma unroll
  for (int i = 0; i < 4; i++){
    int row0 = R + i * 16 + rq;
#pragma unroll
    for (int j = 0; j < 4; j++){
      int col = Cb + j * 16 + cn;
      if (col < N){
#pragma unroll
        for (int r = 0; r < 4; r++){
          int row = row0 + r;
          if (row < M){
            size_t idx = (size_t)row * ldc + col;
            float v = acc[i][j][r];
            C0[idx] = v;
            if (C1o){ C1o[idx] = v; C2o[idx] = v + v; }
          }
        }
      }
    }
  }
}

// ------------------------- small reductions --------------------------------
__global__ __launch_bounds__(256) void k_sum(const float* __restrict__ x, int n, float* __restrict__ out){
  __shared__ float sh[4];
  float s = 0.f;
  for (int i = blockIdx.x * blockDim.x + threadIdx.x; i < n; i += gridDim.x * blockDim.x) s += x[i];
  for (int off = 32; off > 0; off >>= 1) s += __shfl_down(s, off);
  int lane = threadIdx.x & 63, w = threadIdx.x >> 6;
  if (lane == 0) sh[w] = s;
  __syncthreads();
  if (threadIdx.x == 0) atomicAdd(out, sh[0] + sh[1] + sh[2] + sh[3]);
}

// K[h] = sum_c line[h*128+c]*atte[h*128+c]; Kbuf[0..2]=v, Kbuf[3..5]=h
__global__ __launch_bounds__(128) void k_kdot(const float* __restrict__ vl, const float* __restrict__ va,
                                              const float* __restrict__ hl, const float* __restrict__ ha,
                                              float* __restrict__ Kbuf){
  int c = threadIdx.x, lane = c & 63, w = c >> 6;
  __shared__ float sh[2];
  for (int h = 0; h < 3; h++){
    float s = vl[h*128+c] * va[h*128+c];
    for (int off = 32; off > 0; off >>= 1) s += __shfl_down(s, off);
    if (lane == 0) sh[w] = s;
    __syncthreads();
    if (c == 0) Kbuf[h] = sh[0] + sh[1];
    __syncthreads();
    s = hl[h*128+c] * ha[h*128+c];
    for (int off = 32; off > 0; off >>= 1) s += __shfl_down(s, off);
    if (lane == 0) sh[w] = s;
    __syncthreads();
    if (c == 0) Kbuf[3+h] = sh[0] + sh[1];
    __syncthreads();
  }
}

// Was[k*3+h] = sum_c W[k,h*128+c]*a_src[h,c]  (and same for a_dst) — f32 exact
__global__ __launch_bounds__(128) void k_wa(const float* __restrict__ W, const float* __restrict__ aw_s,
                                            const float* __restrict__ aw_d,
                                            float* __restrict__ Was, float* __restrict__ Wad){
  int k = blockIdx.x, c = threadIdx.x;
  int lane = c & 63, w = c >> 6;
  __shared__ float sh[2][2];
  const float* Wr = W + (size_t)k * 384;
  for (int h = 0; h < 3; h++){
    float x = Wr[h*128 + c];
    float s = x * aw_s[h*128 + c], d = x * aw_d[h*128 + c];
    for (int off = 32; off > 0; off >>= 1){ s += __shfl_down(s, off); d += __shfl_down(d, off); }
    if (lane == 0){ sh[w][0] = s; sh[w][1] = d; }
    __syncthreads();
    if (c == 0){ Was[k*3+h] = sh[0][0] + sh[1][0]; Wad[k*3+h] = sh[0][1] + sh[1][1]; }
    __syncthreads();
  }
}

// asrc[n,h] = sum_k x[n,k]*Was[k,h] with x element (n,k) at x[n*rs + k*cs]
__global__ __launch_bounds__(256) void k_nodedot(const float* __restrict__ x, long rs, long cs,
                                                 const float* __restrict__ Was, const float* __restrict__ Wad,
                                                 float* __restrict__ as_o, float* __restrict__ ad_o){
  int n = blockIdx.x, t = threadIdx.x;
  const float* xb = x + (size_t)n * rs;
  float v[6] = {0,0,0,0,0,0};
  for (int k = t; k < 1024; k += 256){
    float xv = xb[(size_t)k * cs];
    v[0] += xv * Was[k*3+0]; v[1] += xv * Was[k*3+1]; v[2] += xv * Was[k*3+2];
    v[3] += xv * Wad[k*3+0]; v[4] += xv * Wad[k*3+1]; v[5] += xv * Wad[k*3+2];
  }
  __shared__ float sh[4][6];
  int lane = t & 63, w = t >> 6;
  for (int off = 32; off > 0; off >>= 1)
#pragma unroll
    for (int i = 0; i < 6; i++) v[i] += __shfl_down(v[i], off);
  if (lane == 0)
#pragma unroll
    for (int i = 0; i < 6; i++) sh[w][i] = v[i];
  __syncthreads();
  if (t < 6){
    float r = sh[0][t] + sh[1][t] + sh[2][t] + sh[3][t];
    if (t < 3) as_o[n*3 + t] = r; else ad_o[n*3 + (t-3)] = r;
  }
}

// ------------------------- CSR build (counting sort by dst) ----------------
__global__ void k_hist(const int* __restrict__ dst, int E, int* __restrict__ cnt){
  for (int e = blockIdx.x * blockDim.x + threadIdx.x; e < E; e += gridDim.x * blockDim.x)
    atomicAdd(&cnt[dst[e]], 1);
}

__global__ __launch_bounds__(256) void k_exscan(const int* __restrict__ cnt, int N, int* __restrict__ starts){
  __shared__ int sh[256];
  int t = threadIdx.x;
  int chunk = (N + 255) >> 8;
  int lo = t * chunk, hi = lo + chunk;
  if (hi > N) hi = N;
  if (lo > N) lo = N;
  int s = 0;
  for (int i = lo; i < hi; i++) s += cnt[i];
  sh[t] = s;
  __syncthreads();
  for (int off = 1; off < 256; off <<= 1){
    int v = (t >= off) ? sh[t - off] : 0;
    __syncthreads();
    sh[t] += v;
    __syncthreads();
  }
  int run = sh[t] - s;              // exclusive prefix
  for (int i = lo; i < hi; i++){ starts[i] = run; run += cnt[i]; }
  if (t == 255) starts[N] = sh[255];
}

__global__ void k_scatter(const int* __restrict__ dst, int E, const int* __restrict__ starts,
                          int* __restrict__ cur, int* __restrict__ sorted){
  for (int e = blockIdx.x * blockDim.x + threadIdx.x; e < E; e += gridDim.x * blockDim.x){
    int d = dst[e];
    int pos = starts[d] + atomicAdd(&cur[d], 1);
    sorted[pos] = e;
  }
}

// ------------------------- edge softmax (3 passes) -------------------------
// raw lives in the d_out alpha slot; layout [E+N, 3], self-loops appended.
__global__ void k_pass1(const int* __restrict__ src, const int* __restrict__ dst, int E, int N,
                        const float* __restrict__ ew, const float* __restrict__ sumw, float invE,
                        const float* __restrict__ Kc,
                        const float* __restrict__ as_, const float* __restrict__ ad_,
                        float* __restrict__ raw, unsigned* __restrict__ amax){
  int tot = E + N;
  for (int e = blockIdx.x * blockDim.x + threadIdx.x; e < tot; e += gridDim.x * blockDim.x){
    int s, d; float wv = 0.f;
    if (e < E){ s = src[e]; d = dst[e]; if (ew) wv = ew[e]; }
    else      { s = d = e - E;          if (ew) wv = sumw[0] * invE; }
#pragma unroll
    for (int h = 0; h < 3; h++){
      float v = as_[s*3+h] + ad_[d*3+h];
      if (Kc) v += wv * Kc[h];
      v = v >= 0.f ? v : 0.2f * v;                 // LeakyReLU(0.2)
      raw[(size_t)e*3 + h] = v;
      atomicMax(&amax[d*3+h], fenc(v));
    }
  }
}

__global__ void k_pass2(const int* __restrict__ dst, int E, int N, float* __restrict__ raw,
                        const unsigned* __restrict__ amax, float* __restrict__ den){
  int tot = E + N;
  for (int e = blockIdx.x * blockDim.x + threadIdx.x; e < tot; e += gridDim.x * blockDim.x){
    int d = e < E ? dst[e] : e - E;
#pragma unroll
    for (int h = 0; h < 3; h++){
      float ex = expf(raw[(size_t)e*3 + h] - fdec(amax[d*3+h]));
      raw[(size_t)e*3 + h] = ex;
      atomicAdd(&den[d*3+h], ex);
    }
  }
}

__global__ void k_pass3(const int* __restrict__ dst, int E, int N, float* __restrict__ raw,
                        const float* __restrict__ den){
  int tot = E + N;
  for (int e = blockIdx.x * blockDim.x + threadIdx.x; e < tot; e += gridDim.x * blockDim.x){
    int d = e < E ? dst[e] : e - E;
#pragma unroll
    for (int h = 0; h < 3; h++)
      raw[(size_t)e*3 + h] = raw[(size_t)e*3 + h] / (den[d*3+h] + 1e-16f);
  }
}

// ------------------------- GAT aggregation ---------------------------------
// feat[n,c] = mean_h( sum_{e->n} xw[src(e),h,c]*alpha[e,h] ) + bias[c]
__global__ __launch_bounds__(128) void k_agg(const float* __restrict__ xw, int ld,
                                             const int* __restrict__ src, const int* __restrict__ sorted,
                                             const int* __restrict__ starts, const float* __restrict__ alpha,
                                             const float* __restrict__ bias, int E,
                                             float* __restrict__ feat){
  int n = blockIdx.x, c = threadIdx.x;
  size_t sl = (size_t)(E + n) * 3;
  float a0 = alpha[sl], a1 = alpha[sl+1], a2 = alpha[sl+2];
  const float* xn = xw + (size_t)n * ld;
  float f0 = xn[c] * a0, f1 = xn[128+c] * a1, f2 = xn[256+c] * a2;   // self-loop
  int i1 = starts[n+1];
  for (int i = starts[n]; i < i1; i++){
    int e = sorted[i];
    int s = src[e];
    size_t eb = (size_t)e * 3;
    float b0 = alpha[eb], b1 = alpha[eb+1], b2 = alpha[eb+2];
    const float* xs = xw + (size_t)s * ld;
    f0 += xs[c] * b0; f1 += xs[128+c] * b1; f2 += xs[256+c] * b2;
  }
  feat[(size_t)n*128 + c] = (f0 + f1 + f2) * (1.f/3.f) + bias[c];
}

// ------------------------- BatchNorm ---------------------------------------
__global__ __launch_bounds__(256) void k_bnstat(const float* __restrict__ C, int ldc, int coff, int M,
                                                float* __restrict__ mean, float* __restrict__ rstd){
  int j = blockIdx.x;
  float s = 0.f, q = 0.f;
  for (int m = threadIdx.x; m < M; m += 256){
    float v = C[(size_t)m*ldc + coff + j];
    s += v; q += v*v;
  }
  __shared__ float sh[4][2];
  int lane = threadIdx.x & 63, w = threadIdx.x >> 6;
  for (int off = 32; off > 0; off >>= 1){ s += __shfl_down(s, off); q += __shfl_down(q, off); }
  if (lane == 0){ sh[w][0] = s; sh[w][1] = q; }
  __syncthreads();
  if (threadIdx.x == 0){
    s = sh[0][0]+sh[1][0]+sh[2][0]+sh[3][0];
    q = sh[0][1]+sh[1][1]+sh[2][1]+sh[3][1];
    float mu = s / M;
    float var = q / M - mu*mu;                 // biased var (ddof=0)
    mean[j] = mu;
    rstd[j] = rsqrtf(var + 1e-5f);
  }
}

__global__ void k_bnapply(const float* __restrict__ C, int ldc, int coff, int M,
                          const float* __restrict__ mean, const float* __restrict__ rstd,
                          const float* __restrict__ g, const float* __restrict__ b,
                          unsigned short* __restrict__ out){
  int tot = M * 128;
  for (int idx = blockIdx.x * blockDim.x + threadIdx.x; idx < tot; idx += gridDim.x * blockDim.x){
    int m = idx >> 7, j = idx & 127;
    float v = (C[(size_t)m*ldc + coff + j] - mean[j]) * rstd[j] * g[j] + b[j];
    v = v >= 0.f ? v : 0.01f * v;              // LeakyReLU(0.01)
    out[idx] = f2bf(v);
  }
}

// ===========================================================================
extern "C" void kernel_launch(void* const* d_in, const int* in_sizes, int n_in,
                              void* d_out, int out_size, void* d_ws, size_t ws_size,
                              hipStream_t stream)
{
  (void)in_sizes; (void)n_in; (void)out_size; (void)ws_size;
  const float* virus  = (const float*)d_in[0];
  const float* hostd  = (const float*)d_in[1];
  const float* coex   = (const float*)d_in[2];
  const float* vew    = (const float*)d_in[3];
  const float* hew    = (const float*)d_in[4];
  const float* vW     = (const float*)d_in[5];
  const float* v_as   = (const float*)d_in[6];
  const float* v_ad   = (const float*)d_in[7];
  const float* v_bias = (const float*)d_in[8];
  const float* v_line = (const float*)d_in[9];
  const float* v_atte = (const float*)d_in[10];
  const float* hW     = (const float*)d_in[11];
  const float* h_as   = (const float*)d_in[12];
  const float* h_ad   = (const float*)d_in[13];
  const float* h_bias = (const float*)d_in[14];
  const float* h_line = (const float*)d_in[15];
  const float* h_atte = (const float*)d_in[16];
  const float* vhW    = (const float*)d_in[17];
  const float* vh_as  = (const float*)d_in[18];
  const float* vh_ad  = (const float*)d_in[19];
  const float* vh_bias= (const float*)d_in[20];
  const float* hvW    = (const float*)d_in[21];
  const float* hv_as  = (const float*)d_in[22];
  const float* hv_ad  = (const float*)d_in[23];
  const float* hv_bias= (const float*)d_in[24];
  const float* linvW  = (const float*)d_in[25];
  // d_in[26] linv_b, d_in[28] linh_b: cancel under BatchNorm mean-subtraction
  const float* linhW  = (const float*)d_in[27];
  const float* bng    = (const float*)d_in[29];
  const float* bnb    = (const float*)d_in[30];
  const int* vei  = (const int*)d_in[31];
  const int* hei  = (const int*)d_in[32];
  const int* cei  = (const int*)d_in[33];   // coexistence_edge_index   (hv GAT)
  const int* ceit = (const int*)d_in[34];   // coexistence_edge_index_t (vh GAT)

  float* out = (float*)d_out;
  float* o0 = out;                           // output_host  [6000,6000]
  float* o1 = out + 36000000ll;              // output_virus
  float* o2 = out + 72000000ll;              // sum
  float* alpha_v  = out + 108000000ll;       // [206000,3]
  float* alpha_h  = alpha_v  + 618000;
  float* alpha_vh = alpha_h  + 618000;       // [33792,3]
  float* alpha_hv = alpha_vh + 101376;
  float* feat_v   = alpha_hv + 101376;       // [6000,128]
  float* feat_h   = feat_v   + 768000;
  float* feat_vh  = feat_h   + 768000;       // [1024,128]
  float* feat_hv  = feat_vh  + 131072;

  // ---------------- workspace carve-up ----------------
  char* wp = (char*)d_ws;
  auto alloc = [&](size_t b) -> void* { void* p = wp; wp += (b + 255) & ~(size_t)255; return p; };
  float* C1 = (float*)alloc((size_t)NV*512*4);       // [virus: xw | lin] f32
  float* C2 = (float*)alloc((size_t)NH*512*4);
  float* C3 = (float*)alloc((size_t)1024*384*4);     // xw_vh
  float* C4 = (float*)alloc((size_t)1024*384*4);     // xw_hv
  unsigned short* Avb  = (unsigned short*)alloc((size_t)NV*1024*2);
  unsigned short* Ahb  = (unsigned short*)alloc((size_t)NH*1024*2);
  unsigned short* Acb  = (unsigned short*)alloc((size_t)1024*1024*2);
  unsigned short* Actb = (unsigned short*)alloc((size_t)1024*1024*2);
  unsigned short* BtV  = (unsigned short*)alloc((size_t)512*1024*2);
  unsigned short* BtH  = (unsigned short*)alloc((size_t)512*1024*2);
  unsigned short* BtVH = (unsigned short*)alloc((size_t)384*1024*2);
  unsigned short* BtHV = (unsigned short*)alloc((size_t)384*1024*2);
  unsigned short* vhb  = (unsigned short*)alloc((size_t)NV*128*2);
  unsigned short* hhb  = (unsigned short*)alloc((size_t)NH*128*2);
  float* asV  = (float*)alloc(NV*3*4);  float* adV  = (float*)alloc(NV*3*4);
  float* asH  = (float*)alloc(NH*3*4);  float* adH  = (float*)alloc(NH*3*4);
  float* asC1 = (float*)alloc(1024*3*4); float* adC1 = (float*)alloc(1024*3*4);
  float* asC2 = (float*)alloc(1024*3*4); float* adC2 = (float*)alloc(1024*3*4);
  float* WasV = (float*)alloc(1024*3*4); float* WadV = (float*)alloc(1024*3*4);
  float* WasH = (float*)alloc(1024*3*4); float* WadH = (float*)alloc(1024*3*4);
  float* WasC1= (float*)alloc(1024*3*4); float* WadC1= (float*)alloc(1024*3*4);
  float* WasC2= (float*)alloc(1024*3*4); float* WadC2= (float*)alloc(1024*3*4);
  int* startsV  = (int*)alloc((NV+1)*4);  int* sortedV  = (int*)alloc((size_t)EV*4);
  int* startsH  = (int*)alloc((NH+1)*4);  int* sortedH  = (int*)alloc((size_t)EH*4);
  int* startsC1 = (int*)alloc(1025*4);    int* sortedC1 = (int*)alloc((size_t)EC*4);
  int* startsC2 = (int*)alloc(1025*4);    int* sortedC2 = (int*)alloc((size_t)EC*4);
  float* meanV = (float*)alloc(512); float* rstdV = (float*)alloc(512);
  float* meanH = (float*)alloc(512); float* rstdH = (float*)alloc(512);
  float* Kbuf  = (float*)alloc(256);
  // zero-init region (single memset)
  char* z0 = wp;
  unsigned* amaxV  = (unsigned*)alloc(NV*3*4);  float* denV  = (float*)alloc(NV*3*4);
  unsigned* amaxH  = (unsigned*)alloc(NH*3*4);  float* denH  = (float*)alloc(NH*3*4);
  unsigned* amaxC1 = (unsigned*)alloc(1024*3*4); float* denC1 = (float*)alloc(1024*3*4);
  unsigned* amaxC2 = (unsigned*)alloc(1024*3*4); float* denC2 = (float*)alloc(1024*3*4);
  int* cntV  = (int*)alloc(NV*4);  int* curV  = (int*)alloc(NV*4);
  int* cntH  = (int*)alloc(NH*4);  int* curH  = (int*)alloc(NH*4);
  int* cntC1 = (int*)alloc(1024*4); int* curC1 = (int*)alloc(1024*4);
  int* cntC2 = (int*)alloc(1024*4); int* curC2 = (int*)alloc(1024*4);
  float* sums = (float*)alloc(256);   // sums[0]=sum(vew), sums[1]=sum(hew)
  hipMemsetAsync(z0, 0, (size_t)(wp - z0), stream);

  const int* vsrc = vei,  *vdst = vei  + EV;
  const int* hsrc = hei,  *hdst = hei  + EH;
  const int* c1src= ceit, *c1dst= ceit + EC;   // vh GAT uses *_t indices
  const int* c2src= cei,  *c2dst= cei  + EC;   // hv GAT uses plain indices

  // ---------------- pack inputs to bf16 / B^T ----------------
  k_cv<<<6000, 256, 0, stream>>>(virus, Avb, NV*1024/4);
  k_cv<<<6000, 256, 0, stream>>>(hostd, Ahb, NH*1024/4);
  k_cv<<<1024, 256, 0, stream>>>(coex,  Acb, 1024*1024/4);
  k_tp<<<1024, 256, 0, stream>>>(coex,  Actb, 1024, 0,   1024*1024); // coex^T
  k_tp<<<512, 256, 0, stream>>>(vW,    BtV, 384, 0,   384*1024);
  k_tp<<<512, 256, 0, stream>>>(linvW, BtV, 128, 384, 128*1024);
  k_tp<<<512, 256, 0, stream>>>(hW,    BtH, 384, 0,   384*1024);
  k_tp<<<512, 256, 0, stream>>>(linhW, BtH, 128, 384, 128*1024);
  k_tp<<<512, 256, 0, stream>>>(vhW,   BtVH, 384, 0,  384*1024);
  k_tp<<<512, 256, 0, stream>>>(hvW,   BtHV, 384, 0,  384*1024);

  // ---------------- xw / lin GEMMs (bf16 MFMA, f32 out) ----------------
  k_gemm_nt<<<dim3(4,47), 256, 0, stream>>>(Avb, BtV, NV, 512, 1024, 1024, 1024, C1, nullptr, nullptr, 512);
  k_gemm_nt<<<dim3(4,47), 256, 0, stream>>>(Ahb, BtH, NH, 512, 1024, 1024, 1024, C2, nullptr, nullptr, 512);
  k_gemm_nt<<<dim3(3,8),  256, 0, stream>>>(Acb,  BtVH, 1024, 384, 1024, 1024, 1024, C3, nullptr, nullptr, 384);
  k_gemm_nt<<<dim3(3,8),  256, 0, stream>>>(Actb, BtHV, 1024, 384, 1024, 1024, 1024, C4, nullptr, nullptr, 384);

  // ---------------- exact-f32 attention scalars ----------------
  k_sum<<<256, 256, 0, stream>>>(vew, EV, &sums[0]);
  k_sum<<<256, 256, 0, stream>>>(hew, EH, &sums[1]);
  k_kdot<<<1, 128, 0, stream>>>(v_line, v_atte, h_line, h_atte, Kbuf);
  k_wa<<<1024, 128, 0, stream>>>(vW,  v_as,  v_ad,  WasV,  WadV);
  k_wa<<<1024, 128, 0, stream>>>(hW,  h_as,  h_ad,  WasH,  WadH);
  k_wa<<<1024, 128, 0, stream>>>(vhW, vh_as, vh_ad, WasC1, WadC1);
  k_wa<<<1024, 128, 0, stream>>>(hvW, hv_as, hv_ad, WasC2, WadC2);
  k_nodedot<<<6000, 256, 0, stream>>>(virus, 1024, 1, WasV,  WadV,  asV,  adV);
  k_nodedot<<<6000, 256, 0, stream>>>(hostd, 1024, 1, WasH,  WadH,  asH,  adH);
  k_nodedot<<<1024, 256, 0, stream>>>(coex,  1024, 1, WasC1, WadC1, asC1, adC1);
  k_nodedot<<<1024, 256, 0, stream>>>(coex,  1, 1024, WasC2, WadC2, asC2, adC2); // coex^T view

  // ---------------- CSR by dst (counting sort) ----------------
  k_hist<<<782, 256, 0, stream>>>(vdst,  EV, cntV);
  k_hist<<<782, 256, 0, stream>>>(hdst,  EH, cntH);
  k_hist<<<128, 256, 0, stream>>>(c1dst, EC, cntC1);
  k_hist<<<128, 256, 0, stream>>>(c2dst, EC, cntC2);
  k_exscan<<<1, 256, 0, stream>>>(cntV,  NV,   startsV);
  k_exscan<<<1, 256, 0, stream>>>(cntH,  NH,   startsH);
  k_exscan<<<1, 256, 0, stream>>>(cntC1, 1024, startsC1);
  k_exscan<<<1, 256, 0, stream>>>(cntC2, 1024, startsC2);
  k_scatter<<<782, 256, 0, stream>>>(vdst,  EV, startsV,  curV,  sortedV);
  k_scatter<<<782, 256, 0, stream>>>(hdst,  EH, startsH,  curH,  sortedH);
  k_scatter<<<128, 256, 0, stream>>>(c1dst, EC, startsC1, curC1, sortedC1);
  k_scatter<<<128, 256, 0, stream>>>(c2dst, EC, startsC2, curC2, sortedC2);

  // ---------------- edge softmax ----------------
  k_pass1<<<805, 256, 0, stream>>>(vsrc, vdst, EV, NV, vew, &sums[0], 1.f/EV, Kbuf,   asV, adV, alpha_v, amaxV);
  k_pass1<<<805, 256, 0, stream>>>(hsrc, hdst, EH, NH, hew, &sums[1], 1.f/EH, Kbuf+3, asH, adH, alpha_h, amaxH);
  k_pass1<<<132, 256, 0, stream>>>(c1src, c1dst, EC, 1024, nullptr, nullptr, 0.f, nullptr, asC1, adC1, alpha_vh, amaxC1);
  k_pass1<<<132, 256, 0, stream>>>(c2src, c2dst, EC, 1024, nullptr, nullptr, 0.f, nullptr, asC2, adC2, alpha_hv, amaxC2);
  k_pass2<<<805, 256, 0, stream>>>(vdst,  EV, NV,   alpha_v,  amaxV,  denV);
  k_pass2<<<805, 256, 0, stream>>>(hdst,  EH, NH,   alpha_h,  amaxH,  denH);
  k_pass2<<<132, 256, 0, stream>>>(c1dst, EC, 1024, alpha_vh, amaxC1, denC1);
  k_pass2<<<132, 256, 0, stream>>>(c2dst, EC, 1024, alpha_hv, amaxC2, denC2);
  k_pass3<<<805, 256, 0, stream>>>(vdst,  EV, NV,   alpha_v,  denV);
  k_pass3<<<805, 256, 0, stream>>>(hdst,  EH, NH,   alpha_h,  denH);
  k_pass3<<<132, 256, 0, stream>>>(c1dst, EC, 1024, alpha_vh, denC1);
  k_pass3<<<132, 256, 0, stream>>>(c2dst, EC, 1024, alpha_hv, denC2);

  // ---------------- aggregation -> feat ----------------
  k_agg<<<6000, 128, 0, stream>>>(C1, 512, vsrc,  sortedV,  startsV,  alpha_v,  v_bias,  EV, feat_v);
  k_agg<<<6000, 128, 0, stream>>>(C2, 512, hsrc,  sortedH,  startsH,  alpha_h,  h_bias,  EH, feat_h);
  k_agg<<<1024, 128, 0, stream>>>(C3, 384, c1src, sortedC1, startsC1, alpha_vh, vh_bias, EC, feat_vh);
  k_agg<<<1024, 128, 0, stream>>>(C4, 384, c2src, sortedC2, startsC2, alpha_hv, hv_bias, EC, feat_hv);

  // ---------------- BN + LeakyReLU(0.01) -> bf16 ----------------
  k_bnstat<<<128, 256, 0, stream>>>(C1, 512, 384, NV, meanV, rstdV);
  k_bnstat<<<128, 256, 0, stream>>>(C2, 512, 384, NH, meanH, rstdH);
  k_bnapply<<<3000, 256, 0, stream>>>(C1, 512, 384, NV, meanV, rstdV, bng, bnb, vhb);
  k_bnapply<<<3000, 256, 0, stream>>>(C2, 512, 384, NH, meanH, rstdH, bng, bnb, hhb);

  // ---------------- final vh @ hh^T with triple write ----------------
  k_gemm_nt<<<dim3(47,47), 256, 0, stream>>>(vhb, hhb, NV, NH, 128, 128, 128, o0, o1, o2, NH);
}

// Round 3
// 957.159 us; speedup vs baseline: 1.3916x; 1.3916x over previous
//
#include <hip/hip_runtime.h>

// ---------------------------------------------------------------------------
// VirusHostCoexistenceModel: 4×GATConv + 2×(Linear+BN+LeakyReLU) + vh@hh^T
#define NV   6000
#define NH   6000
#define HID  128
#define EV   200000
#define EH   200000
#define EC   32768

typedef __attribute__((ext_vector_type(8))) short bf16x8;
typedef __attribute__((ext_vector_type(4))) float f32x4;

__device__ __forceinline__ unsigned short f2bf(float f){
  unsigned u = __float_as_uint(f);
  u += 0x7FFFu + ((u >> 16) & 1u);        // RNE bf16
  return (unsigned short)(u >> 16);
}

// ------------------------- fused pack (f32 -> bf16 rows) -------------------
__global__ __launch_bounds__(256) void k_prep_cv(
    const float* __restrict__ virus, const float* __restrict__ hostd, const float* __restrict__ coex,
    unsigned short* __restrict__ Avb, unsigned short* __restrict__ Ahb, unsigned short* __restrict__ Acb){
  int i = blockIdx.x * 256 + threadIdx.x;      // grid exactly 3334144 float4s
  const float* src; unsigned short* dst; int off;
  if (i < 1536000)      { src = virus; dst = Avb; off = i; }
  else if (i < 3072000) { src = hostd; dst = Ahb; off = i - 1536000; }
  else                  { src = coex;  dst = Acb; off = i - 3072000; }
  float4 v = reinterpret_cast<const float4*>(src)[off];
  ushort4 o; o.x = f2bf(v.x); o.y = f2bf(v.y); o.z = f2bf(v.z); o.w = f2bf(v.w);
  reinterpret_cast<ushort4*>(dst)[off] = o;
}

// ------------------------- fused transpose-to-bf16 -------------------------
// dst[(n+off)*1024 + k] = bf16(src[k*Nc + n])
__global__ __launch_bounds__(256) void k_prep_tp(
    const float* __restrict__ coex, const float* __restrict__ vW, const float* __restrict__ linvW,
    const float* __restrict__ hW, const float* __restrict__ linhW,
    const float* __restrict__ vhW, const float* __restrict__ hvW,
    unsigned short* __restrict__ Actb, unsigned short* __restrict__ BtV,
    unsigned short* __restrict__ BtH, unsigned short* __restrict__ BtVH,
    unsigned short* __restrict__ BtHV){
  int idx = blockIdx.x * 256 + threadIdx.x;    // grid exactly 2883584
  const float* src; unsigned short* dst; int Nc, off, local;
  if      (idx < 1048576){ src=coex;  dst=Actb; Nc=1024; off=0;   local=idx; }
  else if (idx < 1441792){ src=vW;    dst=BtV;  Nc=384;  off=0;   local=idx-1048576; }
  else if (idx < 1572864){ src=linvW; dst=BtV;  Nc=128;  off=384; local=idx-1441792; }
  else if (idx < 1966080){ src=hW;    dst=BtH;  Nc=384;  off=0;   local=idx-1572864; }
  else if (idx < 2097152){ src=linhW; dst=BtH;  Nc=128;  off=384; local=idx-1966080; }
  else if (idx < 2490368){ src=vhW;   dst=BtVH; Nc=384;  off=0;   local=idx-2097152; }
  else                   { src=hvW;   dst=BtHV; Nc=384;  off=0;   local=idx-2490368; }
  int n = local >> 10, k = local & 1023;
  dst[(size_t)(n + off) * 1024 + k] = f2bf(src[(size_t)k * Nc + n]);
}

// ------------------------- NT bf16 MFMA GEMM body --------------------------
template<bool TRIPLE>
__device__ __forceinline__ void gemm_nt_body(
    const unsigned short* __restrict__ A, const unsigned short* __restrict__ B,
    int M, int N, int K, int lda, int ldb,
    float* __restrict__ C0, float* __restrict__ C1o, float* __restrict__ C2o, int ldc,
    int bx, int by)
{
  const int tid  = threadIdx.x;
  const int lane = tid & 63, w = tid >> 6;
  const int wr = w >> 1, wc = w & 1;
  const int R  = by * 128 + wr * 64;
  const int Cb = bx * 128 + wc * 64;
  const int r0 = lane & 15, kg = lane >> 4;

  const unsigned short* pa[4]; const unsigned short* pb[4];
  bool va[4], vb[4];
#pragma unroll
  for (int i = 0; i < 4; i++){
    int row = R + i * 16 + r0;
    va[i] = row < M;
    pa[i] = A + (size_t)(va[i] ? row : 0) * lda + kg * 8;
    int col = Cb + i * 16 + r0;
    vb[i] = col < N;
    pb[i] = B + (size_t)(vb[i] ? col : 0) * ldb + kg * 8;
  }
  const bf16x8 Z8 = {0,0,0,0,0,0,0,0};
  f32x4 acc[4][4];
#pragma unroll
  for (int i = 0; i < 4; i++)
#pragma unroll
    for (int j = 0; j < 4; j++) acc[i][j] = (f32x4){0.f,0.f,0.f,0.f};

  for (int kk = 0; kk < K; kk += 32){
    bf16x8 av[4], bv[4];
#pragma unroll
    for (int i = 0; i < 4; i++){
      bf16x8 ta = *reinterpret_cast<const bf16x8*>(pa[i] + kk);
      bf16x8 tb = *reinterpret_cast<const bf16x8*>(pb[i] + kk);
      av[i] = va[i] ? ta : Z8;
      bv[i] = vb[i] ? tb : Z8;
    }
#pragma unroll
    for (int i = 0; i < 4; i++)
#pragma unroll
      for (int j = 0; j < 4; j++)
        acc[i][j] = __builtin_amdgcn_mfma_f32_16x16x32_bf16(av[i], bv[j], acc[i][j], 0, 0, 0);
  }

  const int cn = lane & 15, rq = (lane >> 4) * 4;
#pragma unroll
  for (int i = 0; i < 4; i++){
    int row0 = R + i * 16 + rq;
#pragma unroll
    for (int j = 0; j < 4; j++){
      int col = Cb + j * 16 + cn;
      if (col < N){
#pragma unroll
        for (int r = 0; r < 4; r++){
          int row = row0 + r;
          if (row < M){
            size_t idx = (size_t)row * ldc + col;
            float v = acc[i][j][r];
            C0[idx] = v;
            if (TRIPLE){ C1o[idx] = v; C2o[idx] = v + v; }
          }
        }
      }
    }
  }
}

// 4 xw GEMMs in one dispatch; z selects the problem
__global__ __launch_bounds__(256) void k_gemm4(
    const unsigned short* A0, const unsigned short* B0, float* Co0,
    const unsigned short* A1, const unsigned short* B1, float* Co1,
    const unsigned short* A2, const unsigned short* B2, float* Co2,
    const unsigned short* A3, const unsigned short* B3, float* Co3)
{
  int z = blockIdx.z;
  if (z == 0)
    gemm_nt_body<false>(A0, B0, NV, 512, 1024, 1024, 1024, Co0, nullptr, nullptr, 512, blockIdx.x, blockIdx.y);
  else if (z == 1)
    gemm_nt_body<false>(A1, B1, NH, 512, 1024, 1024, 1024, Co1, nullptr, nullptr, 512, blockIdx.x, blockIdx.y);
  else {
    if (blockIdx.x >= 3 || blockIdx.y >= 8) return;
    if (z == 2)
      gemm_nt_body<false>(A2, B2, 1024, 384, 1024, 1024, 1024, Co2, nullptr, nullptr, 384, blockIdx.x, blockIdx.y);
    else
      gemm_nt_body<false>(A3, B3, 1024, 384, 1024, 1024, 1024, Co3, nullptr, nullptr, 384, blockIdx.x, blockIdx.y);
  }
}

__global__ __launch_bounds__(256) void k_gemm_final(
    const unsigned short* __restrict__ A, const unsigned short* __restrict__ B,
    float* __restrict__ o0, float* __restrict__ o1, float* __restrict__ o2)
{
  gemm_nt_body<true>(A, B, NV, NH, 128, 128, 128, o0, o1, o2, NH, blockIdx.x, blockIdx.y);
}

// ------------------------- fused scalar prep -------------------------------
// blocks 0..4095: Was/Wad (4 matrices × 1024 rows); 4096..4223: sum(vew);
// 4224..4351: sum(hew); 4352: Kbuf dots.
__global__ __launch_bounds__(128) void k_scal(
    const float* vW, const float* v_as, const float* v_ad,
    const float* hW, const float* h_as, const float* h_ad,
    const float* vhW, const float* vh_as, const float* vh_ad,
    const float* hvW, const float* hv_as, const float* hv_ad,
    float* WasV, float* WadV, float* WasH, float* WadH,
    float* WasC1, float* WadC1, float* WasC2, float* WadC2,
    const float* vew, const float* hew, float* sums,
    const float* v_line, const float* v_atte, const float* h_line, const float* h_atte,
    float* Kbuf)
{
  int b = blockIdx.x, t = threadIdx.x;
  int lane = t & 63, w = t >> 6;
  __shared__ float sh[2][2];
  if (b < 4096){
    const float *W, *as_, *ad_; float *Was, *Wad;
    switch (b >> 10){
      case 0:  W=vW;  as_=v_as;  ad_=v_ad;  Was=WasV;  Wad=WadV;  break;
      case 1:  W=hW;  as_=h_as;  ad_=h_ad;  Was=WasH;  Wad=WadH;  break;
      case 2:  W=vhW; as_=vh_as; ad_=vh_ad; Was=WasC1; Wad=WadC1; break;
      default: W=hvW; as_=hv_as; ad_=hv_ad; Was=WasC2; Wad=WadC2; break;
    }
    int k = b & 1023;
    const float* Wr = W + (size_t)k * 384;
    for (int h = 0; h < 3; h++){
      float x = Wr[h*128 + t];
      float s = x * as_[h*128 + t], d = x * ad_[h*128 + t];
      for (int off = 32; off > 0; off >>= 1){ s += __shfl_down(s, off); d += __shfl_down(d, off); }
      if (lane == 0){ sh[w][0] = s; sh[w][1] = d; }
      __syncthreads();
      if (t == 0){ Was[k*3+h] = sh[0][0] + sh[1][0]; Wad[k*3+h] = sh[0][1] + sh[1][1]; }
      __syncthreads();
    }
  } else if (b < 4352){
    const float* x = (b < 4224) ? vew : hew;
    int slot = (b < 4224) ? 0 : 1;
    int base = (b - 4096) & 127;
    float s = 0.f;
    for (int i = base*128 + t; i < EV; i += 128*128) s += x[i];
    for (int off = 32; off > 0; off >>= 1) s += __shfl_down(s, off);
    if (lane == 0) sh[w][0] = s;
    __syncthreads();
    if (t == 0) atomicAdd(&sums[slot], sh[0][0] + sh[1][0]);
  } else {
    for (int h = 0; h < 3; h++){
      float s = v_line[h*128+t] * v_atte[h*128+t];
      for (int off = 32; off > 0; off >>= 1) s += __shfl_down(s, off);
      if (lane == 0) sh[w][0] = s;
      __syncthreads();
      if (t == 0) Kbuf[h] = sh[0][0] + sh[1][0];
      __syncthreads();
      s = h_line[h*128+t] * h_atte[h*128+t];
      for (int off = 32; off > 0; off >>= 1) s += __shfl_down(s, off);
      if (lane == 0) sh[w][0] = s;
      __syncthreads();
      if (t == 0) Kbuf[3+h] = sh[0][0] + sh[1][0];
      __syncthreads();
    }
  }
}

// ------------------------- node attention dots (row-major x) ---------------
__global__ __launch_bounds__(256) void k_nodedot(
    const float* __restrict__ virus, const float* __restrict__ hostd, const float* __restrict__ coex,
    const float* __restrict__ WasV, const float* __restrict__ WadV,
    const float* __restrict__ WasH, const float* __restrict__ WadH,
    const float* __restrict__ WasC1, const float* __restrict__ WadC1,
    float* asV, float* adV, float* asH, float* adH, float* asC1, float* adC1)
{
  int b = blockIdx.x, t = threadIdx.x;
  const float *xb, *Was, *Wad; float *ao, *doo;
  if (b < 6000)       { int n=b;        xb=virus+(size_t)n*1024; Was=WasV;  Wad=WadV;  ao=asV+n*3;  doo=adV+n*3; }
  else if (b < 12000) { int n=b-6000;   xb=hostd+(size_t)n*1024; Was=WasH;  Wad=WadH;  ao=asH+n*3;  doo=adH+n*3; }
  else                { int n=b-12000;  xb=coex +(size_t)n*1024; Was=WasC1; Wad=WadC1; ao=asC1+n*3; doo=adC1+n*3; }
  float v[6] = {0,0,0,0,0,0};
  for (int k = t; k < 1024; k += 256){
    float xv = xb[k];
    v[0] += xv * Was[k*3+0]; v[1] += xv * Was[k*3+1]; v[2] += xv * Was[k*3+2];
    v[3] += xv * Wad[k*3+0]; v[4] += xv * Wad[k*3+1]; v[5] += xv * Wad[k*3+2];
  }
  __shared__ float sh[4][6];
  int lane = t & 63, w = t >> 6;
  for (int off = 32; off > 0; off >>= 1)
#pragma unroll
    for (int i = 0; i < 6; i++) v[i] += __shfl_down(v[i], off);
  if (lane == 0)
#pragma unroll
    for (int i = 0; i < 6; i++) sh[w][i] = v[i];
  __syncthreads();
  if (t < 6){
    float r = sh[0][t] + sh[1][t] + sh[2][t] + sh[3][t];
    if (t < 3) ao[t] = r; else doo[t-3] = r;
  }
}

// coex^T rows = coex columns: coalesced along n, W·a factors staged in LDS
__global__ __launch_bounds__(256) void k_nodedot_t(
    const float* __restrict__ coex, const float* __restrict__ Was, const float* __restrict__ Wad,
    float* __restrict__ as_, float* __restrict__ ad_)
{
  __shared__ float sw[3072], sd[3072];
  for (int i = threadIdx.x; i < 3072; i += 256){ sw[i] = Was[i]; sd[i] = Wad[i]; }
  __syncthreads();
  int nn = blockIdx.x * 256 + threadIdx.x;     // 0..1023 (grid 4)
  float a0=0,a1=0,a2=0,b0=0,b1=0,b2=0;
  for (int k = 0; k < 1024; k++){
    float xv = coex[(size_t)k*1024 + nn];
    a0 += xv*sw[k*3];   a1 += xv*sw[k*3+1]; a2 += xv*sw[k*3+2];
    b0 += xv*sd[k*3];   b1 += xv*sd[k*3+1]; b2 += xv*sd[k*3+2];
  }
  as_[nn*3]=a0; as_[nn*3+1]=a1; as_[nn*3+2]=a2;
  ad_[nn*3]=b0; ad_[nn*3+1]=b1; ad_[nn*3+2]=b2;
}

// ------------------------- CSR build ---------------------------------------
__global__ __launch_bounds__(256) void k_hist4(
    const int* vd, const int* hd, const int* c1d, const int* c2d,
    int* cV, int* cH, int* c1, int* c2)
{
  int idx = blockIdx.x * 256 + threadIdx.x;
  if (idx >= EV + EH + 2*EC) return;
  const int* dp; int* cnt; int e;
  if      (idx < EV)          { dp=vd;  cnt=cV; e=idx; }
  else if (idx < EV+EH)       { dp=hd;  cnt=cH; e=idx-EV; }
  else if (idx < EV+EH+EC)    { dp=c1d; cnt=c1; e=idx-EV-EH; }
  else                        { dp=c2d; cnt=c2; e=idx-EV-EH-EC; }
  atomicAdd(&cnt[dp[e]], 1);
}

__global__ __launch_bounds__(256) void k_exscan4(
    int* cV, int* sV, int* cH, int* sH, int* c1, int* s1, int* c2, int* s2)
{
  int* cnt; int* st; int N;
  switch (blockIdx.x){
    case 0:  cnt=cV; st=sV; N=NV;   break;
    case 1:  cnt=cH; st=sH; N=NH;   break;
    case 2:  cnt=c1; st=s1; N=1024; break;
    default: cnt=c2; st=s2; N=1024; break;
  }
  __shared__ int sh[256];
  int t = threadIdx.x;
  int chunk = (N + 255) >> 8;
  int lo = t * chunk, hi = lo + chunk;
  if (hi > N) hi = N;
  if (lo > N) lo = N;
  int s = 0;
  for (int i = lo; i < hi; i++) s += cnt[i];
  sh[t] = s;
  __syncthreads();
  for (int off = 1; off < 256; off <<= 1){
    int v = (t >= off) ? sh[t - off] : 0;
    __syncthreads();
    sh[t] += v;
    __syncthreads();
  }
  int run = sh[t] - s;
  for (int i = lo; i < hi; i++){ st[i] = run; run += cnt[i]; }
  if (t == 255) st[N] = sh[255];
}

__global__ __launch_bounds__(256) void k_scatter4(
    const int* vd, const int* hd, const int* c1d, const int* c2d,
    const int* stV, const int* stH, const int* st1, const int* st2,
    int* cuV, int* cuH, int* cu1, int* cu2,
    int* soV, int* soH, int* so1, int* so2)
{
  int idx = blockIdx.x * 256 + threadIdx.x;
  if (idx >= EV + EH + 2*EC) return;
  const int* dp; const int* st; int* cur; int* so; int e;
  if      (idx < EV)       { dp=vd;  st=stV; cur=cuV; so=soV; e=idx; }
  else if (idx < EV+EH)    { dp=hd;  st=stH; cur=cuH; so=soH; e=idx-EV; }
  else if (idx < EV+EH+EC) { dp=c1d; st=st1; cur=cu1; so=so1; e=idx-EV-EH; }
  else                     { dp=c2d; st=st2; cur=cu2; so=so2; e=idx-EV-EH-EC; }
  int d = dp[e];
  so[st[d] + atomicAdd(&cur[d], 1)] = e;
}

// ------------------------- fused GAT: softmax + alpha + aggregate ----------
#define GCAP 512
struct GatDesc {
  const float* xw; const int* src; const int* sorted; const int* starts;
  const float* as_; const float* ad_; const float* Kc; const float* ew; const float* sumw;
  const float* bias; float* alpha; float* feat;
  int ld; int E; float invE;
};

__global__ __launch_bounds__(128) void k_gat(GatDesc d){
  const int n = blockIdx.x, t = threadIdx.x;
  const int lane = t & 63, w = t >> 6;
  __shared__ float shx[GCAP][3];
  __shared__ int   shs[GCAP];
  __shared__ float redA[2][3], redB[2][3];
  const int s0 = d.starts[n];
  const int deg = d.starts[n+1] - s0;
  const bool hasW = (d.ew != nullptr);
  float K0=0.f, K1=0.f, K2=0.f, wself=0.f;
  if (hasW){ K0=d.Kc[0]; K1=d.Kc[1]; K2=d.Kc[2]; wself = d.sumw[0] * d.invE; }
  const float ad0 = d.ad_[n*3], ad1 = d.ad_[n*3+1], ad2 = d.ad_[n*3+2];
  float sr0 = d.as_[n*3+0] + ad0 + wself*K0;  sr0 = sr0 >= 0.f ? sr0 : 0.2f*sr0;
  float sr1 = d.as_[n*3+1] + ad1 + wself*K1;  sr1 = sr1 >= 0.f ? sr1 : 0.2f*sr1;
  float sr2 = d.as_[n*3+2] + ad2 + wself*K2;  sr2 = sr2 >= 0.f ? sr2 : 0.2f*sr2;

  // pass A: raw scores + per-head max (mx seeded with self-loop)
  float mx0 = sr0, mx1 = sr1, mx2 = sr2;
  for (int i = t; i < deg; i += 128){
    int e = d.sorted[s0 + i];
    int s = d.src[e];
    float wv = hasW ? d.ew[e] : 0.f;
    float r0 = d.as_[s*3+0] + ad0 + wv*K0;  r0 = r0 >= 0.f ? r0 : 0.2f*r0;
    float r1 = d.as_[s*3+1] + ad1 + wv*K1;  r1 = r1 >= 0.f ? r1 : 0.2f*r1;
    float r2 = d.as_[s*3+2] + ad2 + wv*K2;  r2 = r2 >= 0.f ? r2 : 0.2f*r2;
    if (i < GCAP){ shs[i] = s; shx[i][0]=r0; shx[i][1]=r1; shx[i][2]=r2; }
    mx0 = fmaxf(mx0, r0); mx1 = fmaxf(mx1, r1); mx2 = fmaxf(mx2, r2);
  }
  for (int off = 32; off > 0; off >>= 1){
    mx0 = fmaxf(mx0, __shfl_down(mx0, off));
    mx1 = fmaxf(mx1, __shfl_down(mx1, off));
    mx2 = fmaxf(mx2, __shfl_down(mx2, off));
  }
  if (lane == 0){ redA[w][0]=mx0; redA[w][1]=mx1; redA[w][2]=mx2; }
  __syncthreads();
  const float M0 = fmaxf(redA[0][0], redA[1][0]);
  const float M1 = fmaxf(redA[0][1], redA[1][1]);
  const float M2 = fmaxf(redA[0][2], redA[1][2]);

  // pass B: exp + sum
  float t0 = 0.f, t1 = 0.f, t2 = 0.f;
  for (int i = t; i < deg; i += 128){
    float r0, r1, r2;
    if (i < GCAP){ r0 = shx[i][0]; r1 = shx[i][1]; r2 = shx[i][2]; }
    else {
      int e = d.sorted[s0 + i]; int s = d.src[e];
      float wv = hasW ? d.ew[e] : 0.f;
      r0 = d.as_[s*3+0] + ad0 + wv*K0; r0 = r0>=0.f?r0:0.2f*r0;
      r1 = d.as_[s*3+1] + ad1 + wv*K1; r1 = r1>=0.f?r1:0.2f*r1;
      r2 = d.as_[s*3+2] + ad2 + wv*K2; r2 = r2>=0.f?r2:0.2f*r2;
    }
    float e0 = expf(r0 - M0), e1 = expf(r1 - M1), e2 = expf(r2 - M2);
    if (i < GCAP){ shx[i][0]=e0; shx[i][1]=e1; shx[i][2]=e2; }
    t0 += e0; t1 += e1; t2 += e2;
  }
  for (int off = 32; off > 0; off >>= 1){
    t0 += __shfl_down(t0, off); t1 += __shfl_down(t1, off); t2 += __shfl_down(t2, off);
  }
  if (lane == 0){ redB[w][0]=t0; redB[w][1]=t1; redB[w][2]=t2; }
  __syncthreads();
  const float se0 = expf(sr0 - M0), se1 = expf(sr1 - M1), se2 = expf(sr2 - M2);
  const float i0 = 1.f / (redB[0][0] + redB[1][0] + se0 + 1e-16f);
  const float i1 = 1.f / (redB[0][1] + redB[1][1] + se1 + 1e-16f);
  const float i2 = 1.f / (redB[0][2] + redB[1][2] + se2 + 1e-16f);

  // pass C: write alpha in original edge order
  for (int i = t; i < deg; i += 128){
    int e = d.sorted[s0 + i];
    float e0, e1, e2;
    if (i < GCAP){ e0 = shx[i][0]; e1 = shx[i][1]; e2 = shx[i][2]; }
    else {
      int s = d.src[e];
      float wv = hasW ? d.ew[e] : 0.f;
      float r0 = d.as_[s*3+0]+ad0+wv*K0; r0=r0>=0.f?r0:0.2f*r0;
      float r1 = d.as_[s*3+1]+ad1+wv*K1; r1=r1>=0.f?r1:0.2f*r1;
      float r2 = d.as_[s*3+2]+ad2+wv*K2; r2=r2>=0.f?r2:0.2f*r2;
      e0 = expf(r0-M0); e1 = expf(r1-M1); e2 = expf(r2-M2);
    }
    float* ap = d.alpha + (size_t)e * 3;
    ap[0] = e0 * i0; ap[1] = e1 * i1; ap[2] = e2 * i2;
  }
  if (t == 0){
    float* ap = d.alpha + (size_t)(d.E + n) * 3;
    ap[0] = se0 * i0; ap[1] = se1 * i1; ap[2] = se2 * i2;
  }

  // pass D: feature aggregation (thread = channel)
  const float* xn = d.xw + (size_t)n * d.ld;
  float f0 = xn[t] * se0, f1 = xn[128+t] * se1, f2 = xn[256+t] * se2;
  for (int i = 0; i < deg; i++){
    int s; float e0, e1, e2;
    if (i < GCAP){ s = shs[i]; e0 = shx[i][0]; e1 = shx[i][1]; e2 = shx[i][2]; }
    else {
      int e = d.sorted[s0 + i]; s = d.src[e];
      float wv = hasW ? d.ew[e] : 0.f;
      float r0 = d.as_[s*3+0]+ad0+wv*K0; r0=r0>=0.f?r0:0.2f*r0;
      float r1 = d.as_[s*3+1]+ad1+wv*K1; r1=r1>=0.f?r1:0.2f*r1;
      float r2 = d.as_[s*3+2]+ad2+wv*K2; r2=r2>=0.f?r2:0.2f*r2;
      e0 = expf(r0-M0); e1 = expf(r1-M1); e2 = expf(r2-M2);
    }
    const float* xs = d.xw + (size_t)s * d.ld;
    f0 += xs[t] * e0; f1 += xs[128+t] * e1; f2 += xs[256+t] * e2;
  }
  d.feat[(size_t)n*128 + t] = (f0*i0 + f1*i1 + f2*i2) * (1.f/3.f) + d.bias[t];
}

// ------------------------- BatchNorm (coalesced) ---------------------------
// bnacc layout: [which][0=sum,1=sq][128]
__global__ __launch_bounds__(128) void k_bnstat(
    const float* __restrict__ C1, const float* __restrict__ C2, float* __restrict__ bnacc)
{
  int which = blockIdx.y, t = threadIdx.x;
  const float* C = which ? C2 : C1;
  int r0 = blockIdx.x * 32;
  float s = 0.f, q = 0.f;
  for (int r = 0; r < 32; r++){
    int row = r0 + r;
    if (row < NV){
      float v = C[(size_t)row * 512 + 384 + t];
      s += v; q += v * v;
    }
  }
  atomicAdd(&bnacc[which*256 + t],       s);
  atomicAdd(&bnacc[which*256 + 128 + t], q);
}

__global__ __launch_bounds__(256) void k_bnfin(
    const float* __restrict__ bnacc, float* meanV, float* rstdV, float* meanH, float* rstdH)
{
  int t = threadIdx.x;
  int which = t >> 7, j = t & 127;
  float mu = bnacc[which*256 + j] * (1.f/NV);
  float var = bnacc[which*256 + 128 + j] * (1.f/NV) - mu*mu;
  if (which == 0){ meanV[j] = mu; rstdV[j] = rsqrtf(var + 1e-5f); }
  else           { meanH[j] = mu; rstdH[j] = rsqrtf(var + 1e-5f); }
}

__global__ __launch_bounds__(256) void k_bnapply(
    const float* __restrict__ C1, const float* __restrict__ C2,
    const float* __restrict__ meanV, const float* __restrict__ rstdV,
    const float* __restrict__ meanH, const float* __restrict__ rstdH,
    const float* __restrict__ g, const float* __restrict__ b,
    unsigned short* __restrict__ vhb, unsigned short* __restrict__ hhb)
{
  int idx = blockIdx.x * 256 + threadIdx.x;     // grid exactly 2*768000
  int which = idx >= 768000;
  int local = which ? idx - 768000 : idx;
  int m = local >> 7, j = local & 127;
  const float* C = which ? C2 : C1;
  const float* mean = which ? meanH : meanV;
  const float* rstd = which ? rstdH : rstdV;
  unsigned short* out = which ? hhb : vhb;
  float v = (C[(size_t)m*512 + 384 + j] - mean[j]) * rstd[j] * g[j] + b[j];
  v = v >= 0.f ? v : 0.01f * v;
  out[local] = f2bf(v);
}

// ===========================================================================
extern "C" void kernel_launch(void* const* d_in, const int* in_sizes, int n_in,
                              void* d_out, int out_size, void* d_ws, size_t ws_size,
                              hipStream_t stream)
{
  (void)in_sizes; (void)n_in; (void)out_size; (void)ws_size;
  const float* virus  = (const float*)d_in[0];
  const float* hostd  = (const float*)d_in[1];
  const float* coex   = (const float*)d_in[2];
  const float* vew    = (const float*)d_in[3];
  const float* hew    = (const float*)d_in[4];
  const float* vW     = (const float*)d_in[5];
  const float* v_as   = (const float*)d_in[6];
  const float* v_ad   = (const float*)d_in[7];
  const float* v_bias = (const float*)d_in[8];
  const float* v_line = (const float*)d_in[9];
  const float* v_atte = (const float*)d_in[10];
  const float* hW     = (const float*)d_in[11];
  const float* h_as   = (const float*)d_in[12];
  const float* h_ad   = (const float*)d_in[13];
  const float* h_bias = (const float*)d_in[14];
  const float* h_line = (const float*)d_in[15];
  const float* h_atte = (const float*)d_in[16];
  const float* vhW    = (const float*)d_in[17];
  const float* vh_as  = (const float*)d_in[18];
  const float* vh_ad  = (const float*)d_in[19];
  const float* vh_bias= (const float*)d_in[20];
  const float* hvW    = (const float*)d_in[21];
  const float* hv_as  = (const float*)d_in[22];
  const float* hv_ad  = (const float*)d_in[23];
  const float* hv_bias= (const float*)d_in[24];
  const float* linvW  = (const float*)d_in[25];
  const float* linhW  = (const float*)d_in[27];   // biases 26/28 cancel in BN
  const float* bng    = (const float*)d_in[29];
  const float* bnb    = (const float*)d_in[30];
  const int* vei  = (const int*)d_in[31];
  const int* hei  = (const int*)d_in[32];
  const int* cei  = (const int*)d_in[33];
  const int* ceit = (const int*)d_in[34];

  float* out = (float*)d_out;
  float* o0 = out;
  float* o1 = out + 36000000ll;
  float* o2 = out + 72000000ll;
  float* alpha_v  = out + 108000000ll;
  float* alpha_h  = alpha_v  + 618000;
  float* alpha_vh = alpha_h  + 618000;
  float* alpha_hv = alpha_vh + 101376;
  float* feat_v   = alpha_hv + 101376;
  float* feat_h   = feat_v   + 768000;
  float* feat_vh  = feat_h   + 768000;
  float* feat_hv  = feat_vh  + 131072;

  // ---------------- workspace carve-up ----------------
  char* wp = (char*)d_ws;
  auto alloc = [&](size_t b) -> void* { void* p = wp; wp += (b + 255) & ~(size_t)255; return p; };
  float* C1 = (float*)alloc((size_t)NV*512*4);
  float* C2 = (float*)alloc((size_t)NH*512*4);
  float* C3 = (float*)alloc((size_t)1024*384*4);
  float* C4 = (float*)alloc((size_t)1024*384*4);
  unsigned short* Avb  = (unsigned short*)alloc((size_t)NV*1024*2);
  unsigned short* Ahb  = (unsigned short*)alloc((size_t)NH*1024*2);
  unsigned short* Acb  = (unsigned short*)alloc((size_t)1024*1024*2);
  unsigned short* Actb = (unsigned short*)alloc((size_t)1024*1024*2);
  unsigned short* BtV  = (unsigned short*)alloc((size_t)512*1024*2);
  unsigned short* BtH  = (unsigned short*)alloc((size_t)512*1024*2);
  unsigned short* BtVH = (unsigned short*)alloc((size_t)384*1024*2);
  unsigned short* BtHV = (unsigned short*)alloc((size_t)384*1024*2);
  unsigned short* vhb  = (unsigned short*)alloc((size_t)NV*128*2);
  unsigned short* hhb  = (unsigned short*)alloc((size_t)NH*128*2);
  float* asV  = (float*)alloc(NV*3*4);   float* adV  = (float*)alloc(NV*3*4);
  float* asH  = (float*)alloc(NH*3*4);   float* adH  = (float*)alloc(NH*3*4);
  float* asC1 = (float*)alloc(1024*3*4); float* adC1 = (float*)alloc(1024*3*4);
  float* asC2 = (float*)alloc(1024*3*4); float* adC2 = (float*)alloc(1024*3*4);
  float* WasV = (float*)alloc(1024*3*4); float* WadV = (float*)alloc(1024*3*4);
  float* WasH = (float*)alloc(1024*3*4); float* WadH = (float*)alloc(1024*3*4);
  float* WasC1= (float*)alloc(1024*3*4); float* WadC1= (float*)alloc(1024*3*4);
  float* WasC2= (float*)alloc(1024*3*4); float* WadC2= (float*)alloc(1024*3*4);
  int* startsV  = (int*)alloc((NV+1)*4);  int* sortedV  = (int*)alloc((size_t)EV*4);
  int* startsH  = (int*)alloc((NH+1)*4);  int* sortedH  = (int*)alloc((size_t)EH*4);
  int* startsC1 = (int*)alloc(1025*4);    int* sortedC1 = (int*)alloc((size_t)EC*4);
  int* startsC2 = (int*)alloc(1025*4);    int* sortedC2 = (int*)alloc((size_t)EC*4);
  float* meanV = (float*)alloc(512); float* rstdV = (float*)alloc(512);
  float* meanH = (float*)alloc(512); float* rstdH = (float*)alloc(512);
  float* Kbuf  = (float*)alloc(256);
  // zero-init region
  char* z0 = wp;
  int* cntV  = (int*)alloc(NV*4);   int* curV  = (int*)alloc(NV*4);
  int* cntH  = (int*)alloc(NH*4);   int* curH  = (int*)alloc(NH*4);
  int* cntC1 = (int*)alloc(1024*4); int* curC1 = (int*)alloc(1024*4);
  int* cntC2 = (int*)alloc(1024*4); int* curC2 = (int*)alloc(1024*4);
  float* sums  = (float*)alloc(256);
  float* bnacc = (float*)alloc(2*256*4);
  hipMemsetAsync(z0, 0, (size_t)(wp - z0), stream);

  const int* vsrc = vei,  *vdst = vei  + EV;
  const int* hsrc = hei,  *hdst = hei  + EH;
  const int* c1src= ceit, *c1dst= ceit + EC;   // vh GAT: transposed indices
  const int* c2src= cei,  *c2dst= cei  + EC;   // hv GAT: plain indices

  // 1-2: pack + transpose
  k_prep_cv<<<13024, 256, 0, stream>>>(virus, hostd, coex, Avb, Ahb, Acb);
  k_prep_tp<<<11264, 256, 0, stream>>>(coex, vW, linvW, hW, linhW, vhW, hvW,
                                       Actb, BtV, BtH, BtVH, BtHV);
  // 3: all four xw/lin GEMMs
  k_gemm4<<<dim3(4,47,4), 256, 0, stream>>>(Avb, BtV, C1, Ahb, BtH, C2,
                                            Acb, BtVH, C3, Actb, BtHV, C4);
  // 4: scalar prep (Was/Wad, edge-weight sums, Kbuf)
  k_scal<<<4353, 128, 0, stream>>>(vW, v_as, v_ad, hW, h_as, h_ad,
                                   vhW, vh_as, vh_ad, hvW, hv_as, hv_ad,
                                   WasV, WadV, WasH, WadH, WasC1, WadC1, WasC2, WadC2,
                                   vew, hew, sums, v_line, v_atte, h_line, h_atte, Kbuf);
  // 5-6: node attention dots
  k_nodedot<<<13024, 256, 0, stream>>>(virus, hostd, coex,
                                       WasV, WadV, WasH, WadH, WasC1, WadC1,
                                       asV, adV, asH, adH, asC1, adC1);
  k_nodedot_t<<<4, 256, 0, stream>>>(coex, WasC2, WadC2, asC2, adC2);
  // 7-9: CSR build
  k_hist4<<<1819, 256, 0, stream>>>(vdst, hdst, c1dst, c2dst, cntV, cntH, cntC1, cntC2);
  k_exscan4<<<4, 256, 0, stream>>>(cntV, startsV, cntH, startsH, cntC1, startsC1, cntC2, startsC2);
  k_scatter4<<<1819, 256, 0, stream>>>(vdst, hdst, c1dst, c2dst,
                                       startsV, startsH, startsC1, startsC2,
                                       curV, curH, curC1, curC2,
                                       sortedV, sortedH, sortedC1, sortedC2);
  // 10-13: fused GAT (softmax + alpha + aggregate)
  {
    GatDesc dv = { C1, vsrc, sortedV, startsV, asV, adV, Kbuf,   vew, &sums[0], v_bias,
                   alpha_v, feat_v, 512, EV, 1.f/EV };
    GatDesc dh = { C2, hsrc, sortedH, startsH, asH, adH, Kbuf+3, hew, &sums[1], h_bias,
                   alpha_h, feat_h, 512, EH, 1.f/EH };
    GatDesc d1 = { C3, c1src, sortedC1, startsC1, asC1, adC1, nullptr, nullptr, nullptr, vh_bias,
                   alpha_vh, feat_vh, 384, EC, 0.f };
    GatDesc d2 = { C4, c2src, sortedC2, startsC2, asC2, adC2, nullptr, nullptr, nullptr, hv_bias,
                   alpha_hv, feat_hv, 384, EC, 0.f };
    k_gat<<<NV,   128, 0, stream>>>(dv);
    k_gat<<<NH,   128, 0, stream>>>(dh);
    k_gat<<<1024, 128, 0, stream>>>(d1);
    k_gat<<<1024, 128, 0, stream>>>(d2);
  }
  // 14-16: BatchNorm + LeakyReLU -> bf16
  k_bnstat<<<dim3(188,2), 128, 0, stream>>>(C1, C2, bnacc);
  k_bnfin<<<1, 256, 0, stream>>>(bnacc, meanV, rstdV, meanH, rstdH);
  k_bnapply<<<6000, 256, 0, stream>>>(C1, C2, meanV, rstdV, meanH, rstdH, bng, bnb, vhb, hhb);
  // 17: final vh @ hh^T triple-write
  k_gemm_final<<<dim3(47,47), 256, 0, stream>>>(vhb, hhb, o0, o1, o2);
}

// Round 4
// 835.921 us; speedup vs baseline: 1.5935x; 1.1450x over previous
//
#include <hip/hip_runtime.h>

// ---------------------------------------------------------------------------
// VirusHostCoexistenceModel — 6-node graph:
//   memset -> k_prep -> k_nd -> k_sg -> k_gatbn -> k_fin
#define NV   6000
#define NH   6000
#define EV   200000
#define EH   200000
#define EC   32768
#define GCAP 256

typedef __attribute__((ext_vector_type(8))) short bf16x8;
typedef __attribute__((ext_vector_type(4))) float f32x4;

__device__ __forceinline__ unsigned short f2bf(float f){
  unsigned u = __float_as_uint(f);
  u += 0x7FFFu + ((u >> 16) & 1u);        // RNE bf16
  return (unsigned short)(u >> 16);
}
__device__ __forceinline__ float bf2f(unsigned short h){
  return __uint_as_float((unsigned)h << 16);
}

// ===========================================================================
// Dispatch 1: pack-to-bf16 + LDS-tiled transposes + W·a scalars + edge hist
// blocks: [0,13024) cv | [13024,13728) tp | [13728,15776) scal
//         [15776,17595) hist | [17595,17851) ew-sums | 17851 kbuf
__global__ __launch_bounds__(256) void k_prep(
    const float* __restrict__ virus, const float* __restrict__ hostd, const float* __restrict__ coex,
    const float* __restrict__ vW, const float* __restrict__ linvW,
    const float* __restrict__ hW, const float* __restrict__ linhW,
    const float* __restrict__ vhW, const float* __restrict__ hvW,
    const float* __restrict__ v_as, const float* __restrict__ v_ad,
    const float* __restrict__ h_as, const float* __restrict__ h_ad,
    const float* __restrict__ vh_as, const float* __restrict__ vh_ad,
    const float* __restrict__ hv_as, const float* __restrict__ hv_ad,
    const float* __restrict__ vew, const float* __restrict__ hew,
    const float* __restrict__ v_line, const float* __restrict__ v_atte,
    const float* __restrict__ h_line, const float* __restrict__ h_atte,
    const int* __restrict__ vdst, const int* __restrict__ hdst,
    const int* __restrict__ c1dst, const int* __restrict__ c2dst,
    unsigned short* Avb, unsigned short* Ahb, unsigned short* Acb,
    unsigned short* Actb, unsigned short* BtV, unsigned short* BtH,
    unsigned short* BtVH, unsigned short* BtHV,
    float* WasV, float* WadV, float* WasH, float* WadH,
    float* WasC1, float* WadC1, float* WasC2, float* WadC2,
    float* sums, float* Kbuf,
    int* cntV, int* cntH, int* cntC1, int* cntC2)
{
  __shared__ float tp_lds[64][65];
  __shared__ float red4[4][2];
  int b = blockIdx.x, t = threadIdx.x;
  int lane = t & 63, w = t >> 6;

  if (b < 13024){                                   // ---- pack f32 -> bf16
    int i = b * 256 + t;                            // 3,334,144 float4s exact
    const float* src; unsigned short* dst; int off;
    if (i < 1536000)      { src = virus; dst = Avb; off = i; }
    else if (i < 3072000) { src = hostd; dst = Ahb; off = i - 1536000; }
    else                  { src = coex;  dst = Acb; off = i - 3072000; }
    float4 v = reinterpret_cast<const float4*>(src)[off];
    ushort4 o; o.x = f2bf(v.x); o.y = f2bf(v.y); o.z = f2bf(v.z); o.w = f2bf(v.w);
    reinterpret_cast<ushort4*>(dst)[off] = o;
    return;
  }
  b -= 13024;
  if (b < 704){                                     // ---- tiled transpose
    const float* src; unsigned short* dst; int Nc, roff, ntn, rel;
    if      (b < 256){ src=coex;  dst=Actb; Nc=1024; roff=0;   ntn=16; rel=b; }
    else if (b < 352){ src=vW;    dst=BtV;  Nc=384;  roff=0;   ntn=6;  rel=b-256; }
    else if (b < 384){ src=linvW; dst=BtV;  Nc=128;  roff=384; ntn=2;  rel=b-352; }
    else if (b < 480){ src=hW;    dst=BtH;  Nc=384;  roff=0;   ntn=6;  rel=b-384; }
    else if (b < 512){ src=linhW; dst=BtH;  Nc=128;  roff=384; ntn=2;  rel=b-480; }
    else if (b < 608){ src=vhW;   dst=BtVH; Nc=384;  roff=0;   ntn=6;  rel=b-512; }
    else             { src=hvW;   dst=BtHV; Nc=384;  roff=0;   ntn=6;  rel=b-608; }
    int tn = rel % ntn, tk = rel / ntn;             // 16 k-tiles each (1024/64)
    int k0 = tk * 64, n0 = tn * 64;
    int tx = t & 63, ty = t >> 6;
#pragma unroll
    for (int r = 0; r < 16; r++)                    // all dims are ×64 exact
      tp_lds[ty + r*4][tx] = src[(size_t)(k0 + ty + r*4) * Nc + n0 + tx];
    __syncthreads();
#pragma unroll
    for (int r = 0; r < 16; r++)
      dst[(size_t)(n0 + ty + r*4 + roff) * 1024 + k0 + tx] = f2bf(tp_lds[tx][ty + r*4]);
    return;
  }
  b -= 704;
  if (b < 2048){                                    // ---- Was/Wad (2 rows/block)
    int m = b >> 9;
    int krow = (b & 511) * 2 + (t >> 7);
    int c = t & 127;
    const float *W, *as_, *ad_; float *Was, *Wad;
    switch (m){
      case 0:  W=vW;  as_=v_as;  ad_=v_ad;  Was=WasV;  Wad=WadV;  break;
      case 1:  W=hW;  as_=h_as;  ad_=h_ad;  Was=WasH;  Wad=WadH;  break;
      case 2:  W=vhW; as_=vh_as; ad_=vh_ad; Was=WasC1; Wad=WadC1; break;
      default: W=hvW; as_=hv_as; ad_=hv_ad; Was=WasC2; Wad=WadC2; break;
    }
    const float* Wr = W + (size_t)krow * 384;
    for (int h = 0; h < 3; h++){
      float x = Wr[h*128 + c];
      float s = x * as_[h*128 + c], d = x * ad_[h*128 + c];
      for (int off = 32; off > 0; off >>= 1){ s += __shfl_down(s, off); d += __shfl_down(d, off); }
      if (lane == 0){ red4[w][0] = s; red4[w][1] = d; }
      __syncthreads();
      if (t == 0)  { Was[krow*3+h] = red4[0][0] + red4[1][0]; Wad[krow*3+h] = red4[0][1] + red4[1][1]; }
      if (t == 128){ Was[krow*3+h] = red4[2][0] + red4[3][0]; Wad[krow*3+h] = red4[2][1] + red4[3][1]; }
      __syncthreads();
    }
    return;
  }
  b -= 2048;
  if (b < 1819){                                    // ---- degree histogram
    int idx = b * 256 + t;
    if (idx >= EV + EH + 2*EC) return;
    const int* dp; int* cnt; int e;
    if      (idx < EV)       { dp=vdst;  cnt=cntV;  e=idx; }
    else if (idx < EV+EH)    { dp=hdst;  cnt=cntH;  e=idx-EV; }
    else if (idx < EV+EH+EC) { dp=c1dst; cnt=cntC1; e=idx-EV-EH; }
    else                     { dp=c2dst; cnt=cntC2; e=idx-EV-EH-EC; }
    atomicAdd(&cnt[dp[e]], 1);
    return;
  }
  b -= 1819;
  if (b < 256){                                     // ---- edge-weight sums
    int which = b >> 7, base = b & 127;
    const float* x = which ? hew : vew;
    float s = 0.f;
    for (int i = base*256 + t; i < EV; i += 128*256) s += x[i];
    for (int off = 32; off > 0; off >>= 1) s += __shfl_down(s, off);
    if (lane == 0) red4[w][0] = s;
    __syncthreads();
    if (t == 0) atomicAdd(&sums[which], red4[0][0]+red4[1][0]+red4[2][0]+red4[3][0]);
    return;
  }
  // ---- Kbuf dots (single block)
  for (int h = 0; h < 3; h++){
    float s = (t < 128) ? v_line[h*128+t] * v_atte[h*128+t] : 0.f;
    for (int off = 32; off > 0; off >>= 1) s += __shfl_down(s, off);
    if (lane == 0) red4[w][0] = s;
    __syncthreads();
    if (t == 0) Kbuf[h] = red4[0][0]+red4[1][0]+red4[2][0]+red4[3][0];
    __syncthreads();
    s = (t < 128) ? h_line[h*128+t] * h_atte[h*128+t] : 0.f;
    for (int off = 32; off > 0; off >>= 1) s += __shfl_down(s, off);
    if (lane == 0) red4[w][0] = s;
    __syncthreads();
    if (t == 0) Kbuf[3+h] = red4[0][0]+red4[1][0]+red4[2][0]+red4[3][0];
    __syncthreads();
  }
}

// ===========================================================================
// Dispatch 2: exclusive scans + node attention dots (+ coex^T dots)
// blocks: [0,4) exscan | [4,13028) nodedot | [13028,13060) nodedot_t
__global__ __launch_bounds__(256) void k_nd(
    int* cntV, int* startsV, int* cntH, int* startsH,
    int* cntC1, int* startsC1, int* cntC2, int* startsC2,
    const float* __restrict__ virus, const float* __restrict__ hostd, const float* __restrict__ coex,
    const float* __restrict__ WasV, const float* __restrict__ WadV,
    const float* __restrict__ WasH, const float* __restrict__ WadH,
    const float* __restrict__ WasC1, const float* __restrict__ WadC1,
    const float* __restrict__ WasC2, const float* __restrict__ WadC2,
    float* asV, float* adV, float* asH, float* adH,
    float* asC1, float* adC1, float* asC2, float* adC2)
{
  __shared__ int   ssc[256];
  __shared__ float sh6[4][6];
  __shared__ float st[8][32][6];
  int b = blockIdx.x, t = threadIdx.x;

  if (b < 4){                                       // ---- exclusive scan
    int* cnt; int* st_; int N;
    switch (b){
      case 0:  cnt=cntV;  st_=startsV;  N=NV;   break;
      case 1:  cnt=cntH;  st_=startsH;  N=NH;   break;
      case 2:  cnt=cntC1; st_=startsC1; N=1024; break;
      default: cnt=cntC2; st_=startsC2; N=1024; break;
    }
    int chunk = (N + 255) >> 8;
    int lo = t * chunk, hi = lo + chunk;
    if (hi > N) hi = N;
    if (lo > N) lo = N;
    int s = 0;
    for (int i = lo; i < hi; i++) s += cnt[i];
    ssc[t] = s;
    __syncthreads();
    for (int off = 1; off < 256; off <<= 1){
      int v = (t >= off) ? ssc[t - off] : 0;
      __syncthreads();
      ssc[t] += v;
      __syncthreads();
    }
    int run = ssc[t] - s;
    for (int i = lo; i < hi; i++){ st_[i] = run; run += cnt[i]; }
    if (t == 255) st_[N] = ssc[255];
    return;
  }
  b -= 4;
  if (b < 13024){                                   // ---- node dots (row-major x)
    const float *xb, *Was, *Wad; float *ao, *doo;
    if (b < 6000)       { xb=virus+(size_t)b*1024;        Was=WasV;  Wad=WadV;  ao=asV+b*3;          doo=adV+b*3; }
    else if (b < 12000) { int n=b-6000;  xb=hostd+(size_t)n*1024; Was=WasH;  Wad=WadH;  ao=asH+n*3;  doo=adH+n*3; }
    else                { int n=b-12000; xb=coex +(size_t)n*1024; Was=WasC1; Wad=WadC1; ao=asC1+n*3; doo=adC1+n*3; }
    float v[6] = {0,0,0,0,0,0};
    for (int k = t; k < 1024; k += 256){
      float xv = xb[k];
      v[0] += xv*Was[k*3+0]; v[1] += xv*Was[k*3+1]; v[2] += xv*Was[k*3+2];
      v[3] += xv*Wad[k*3+0]; v[4] += xv*Wad[k*3+1]; v[5] += xv*Wad[k*3+2];
    }
    int lane = t & 63, w = t >> 6;
    for (int off = 32; off > 0; off >>= 1)
#pragma unroll
      for (int i = 0; i < 6; i++) v[i] += __shfl_down(v[i], off);
    if (lane == 0)
#pragma unroll
      for (int i = 0; i < 6; i++) sh6[w][i] = v[i];
    __syncthreads();
    if (t < 6){
      float r = sh6[0][t] + sh6[1][t] + sh6[2][t] + sh6[3][t];
      if (t < 3) ao[t] = r; else doo[t-3] = r;
    }
    return;
  }
  b -= 13024;                                       // ---- coex^T dots, 32 blocks
  int c = t & 31, ks = t >> 5;
  int nn = b * 32 + c;
  float a[6] = {0,0,0,0,0,0};
  for (int k = ks*128; k < ks*128 + 128; k++){
    float xv = coex[(size_t)k*1024 + nn];
    a[0] += xv*WasC2[k*3+0]; a[1] += xv*WasC2[k*3+1]; a[2] += xv*WasC2[k*3+2];
    a[3] += xv*WadC2[k*3+0]; a[4] += xv*WadC2[k*3+1]; a[5] += xv*WadC2[k*3+2];
  }
#pragma unroll
  for (int j = 0; j < 6; j++) st[ks][c][j] = a[j];
  __syncthreads();
  if (t < 32){
    float r[6] = {0,0,0,0,0,0};
#pragma unroll
    for (int k = 0; k < 8; k++)
#pragma unroll
      for (int j = 0; j < 6; j++) r[j] += st[k][t][j];
    int n2 = b * 32 + t;
    asC2[n2*3] = r[0]; asC2[n2*3+1] = r[1]; asC2[n2*3+2] = r[2];
    adC2[n2*3] = r[3]; adC2[n2*3+1] = r[4]; adC2[n2*3+2] = r[5];
  }
}

// ===========================================================================
// NT bf16 MFMA GEMM body (K=1024). MODE 0: cols<384 -> bf16 xwb, cols>=384 ->
// f32 lin (ld 128). MODE 1: all cols -> bf16 xwb.
template<int MODE>
__device__ __forceinline__ void gemm_body(
    const unsigned short* __restrict__ A, const unsigned short* __restrict__ B,
    int M, int N, unsigned short* __restrict__ xwb, float* __restrict__ lin,
    int bx, int by)
{
  const int tid  = threadIdx.x;
  const int lane = tid & 63, w = tid >> 6;
  const int wr = w >> 1, wc = w & 1;
  const int R  = by * 128 + wr * 64;
  const int Cb = bx * 128 + wc * 64;
  const int r0 = lane & 15, kg = lane >> 4;

  const unsigned short* pa[4]; const unsigned short* pb[4];
  bool va[4], vb[4];
#pragma unroll
  for (int i = 0; i < 4; i++){
    int row = R + i * 16 + r0;
    va[i] = row < M;
    pa[i] = A + (size_t)(va[i] ? row : 0) * 1024 + kg * 8;
    int col = Cb + i * 16 + r0;
    vb[i] = col < N;
    pb[i] = B + (size_t)(vb[i] ? col : 0) * 1024 + kg * 8;
  }
  const bf16x8 Z8 = {0,0,0,0,0,0,0,0};
  f32x4 acc[4][4];
#pragma unroll
  for (int i = 0; i < 4; i++)
#pragma unroll
    for (int j = 0; j < 4; j++) acc[i][j] = (f32x4){0.f,0.f,0.f,0.f};

  for (int kk = 0; kk < 1024; kk += 32){
    bf16x8 av[4], bv[4];
#pragma unroll
    for (int i = 0; i < 4; i++){
      bf16x8 ta = *reinterpret_cast<const bf16x8*>(pa[i] + kk);
      bf16x8 tb = *reinterpret_cast<const bf16x8*>(pb[i] + kk);
      av[i] = va[i] ? ta : Z8;
      bv[i] = vb[i] ? tb : Z8;
    }
#pragma unroll
    for (int i = 0; i < 4; i++)
#pragma unroll
      for (int j = 0; j < 4; j++)
        acc[i][j] = __builtin_amdgcn_mfma_f32_16x16x32_bf16(av[i], bv[j], acc[i][j], 0, 0, 0);
  }

  const int cn = lane & 15, rq = (lane >> 4) * 4;
#pragma unroll
  for (int i = 0; i < 4; i++){
    int row0 = R + i * 16 + rq;
#pragma unroll
    for (int j = 0; j < 4; j++){
      int col = Cb + j * 16 + cn;
      if (col < N){
#pragma unroll
        for (int r = 0; r < 4; r++){
          int row = row0 + r;
          if (row < M){
            float v = acc[i][j][r];
            if (MODE == 0){
              if (col < 384) xwb[(size_t)row * 384 + col] = f2bf(v);
              else           lin[(size_t)row * 128 + col - 384] = v;
            } else {
              xwb[(size_t)row * 384 + col] = f2bf(v);
            }
          }
        }
      }
    }
  }
}

// Dispatch 3: 4 xw/lin GEMMs + CSR scatter
// blocks: [0,424) gemm | [424,2243) scatter
__global__ __launch_bounds__(256) void k_sg(
    const unsigned short* Avb, const unsigned short* BtV, unsigned short* xwbV, float* linV,
    const unsigned short* Ahb, const unsigned short* BtH, unsigned short* xwbH, float* linH,
    const unsigned short* Acb,  const unsigned short* BtVH, unsigned short* xwbC1,
    const unsigned short* Actb, const unsigned short* BtHV, unsigned short* xwbC2,
    const int* vdst, const int* hdst, const int* c1dst, const int* c2dst,
    const int* stV, const int* stH, const int* st1, const int* st2,
    int* cuV, int* cuH, int* cu1, int* cu2,
    int* soV, int* soH, int* so1, int* so2)
{
  int b = blockIdx.x;
  if (b < 424){
    if (b < 188)      gemm_body<0>(Avb,  BtV,  NV,   512, xwbV,  linV, b & 3, b >> 2);
    else if (b < 376){ int g = b - 188; gemm_body<0>(Ahb,  BtH,  NH,   512, xwbH,  linH, g & 3, g >> 2); }
    else if (b < 400){ int g = b - 376; gemm_body<1>(Acb,  BtVH, 1024, 384, xwbC1, nullptr, g % 3, g / 3); }
    else             { int g = b - 400; gemm_body<1>(Actb, BtHV, 1024, 384, xwbC2, nullptr, g % 3, g / 3); }
    return;
  }
  int idx = (b - 424) * 256 + threadIdx.x;
  if (idx >= EV + EH + 2*EC) return;
  const int* dp; const int* st; int* cur; int* so; int e;
  if      (idx < EV)       { dp=vdst;  st=stV; cur=cuV; so=soV; e=idx; }
  else if (idx < EV+EH)    { dp=hdst;  st=stH; cur=cuH; so=soH; e=idx-EV; }
  else if (idx < EV+EH+EC) { dp=c1dst; st=st1; cur=cu1; so=so1; e=idx-EV-EH; }
  else                     { dp=c2dst; st=st2; cur=cu2; so=so2; e=idx-EV-EH-EC; }
  int d = dp[e];
  so[st[d] + atomicAdd(&cur[d], 1)] = e;
}

// ===========================================================================
// Dispatch 4: fused GAT (softmax + alpha + aggregate, all 4 graphs) + BN stats
struct GatDesc {
  const unsigned short* xwb; const int* src; const int* sorted; const int* starts;
  const float* as_; const float* ad_; const float* Kc; const float* ew; const float* sumw;
  const float* bias; float* alpha; float* feat;
  int E; float invE;
};

__global__ __launch_bounds__(256) void k_gatbn(
    GatDesc dV, GatDesc dH, GatDesc d1, GatDesc d2,
    const float* __restrict__ linV, const float* __restrict__ linH, float* __restrict__ bnacc)
{
  int b = blockIdx.x, t = threadIdx.x;
  if (b >= 14048){                                  // ---- BN stats
    int bb = b - 14048;
    int which = bb >= 188;
    int r0 = (which ? bb - 188 : bb) * 32 + (t >> 7) * 16;
    int c = t & 127;
    const float* lin = which ? linH : linV;
    float s = 0.f, q = 0.f;
#pragma unroll
    for (int r = 0; r < 16; r++){
      int row = r0 + r;
      if (row < NV){
        float v = lin[(size_t)row * 128 + c];
        s += v; q += v * v;
      }
    }
    atomicAdd(&bnacc[which*256 + c],       s);
    atomicAdd(&bnacc[which*256 + 128 + c], q);
    return;
  }
  GatDesc d; int n;
  if (b < 6000)       { d = dV; n = b; }
  else if (b < 12000) { d = dH; n = b - 6000; }
  else if (b < 13024) { d = d1; n = b - 12000; }
  else                { d = d2; n = b - 13024; }

  const int lane = t & 63, w = t >> 6;
  const int c = t & 127, half = t >> 7;
  __shared__ float shx[GCAP][3];
  __shared__ int   shs[GCAP];
  __shared__ float redm[4][3], reds[4][3], shD[128][3];

  const int s0  = d.starts[n];
  const int deg = d.starts[n+1] - s0;
  const bool hasW = (d.ew != nullptr);
  float K0=0.f, K1=0.f, K2=0.f, wself=0.f;
  if (hasW){ K0=d.Kc[0]; K1=d.Kc[1]; K2=d.Kc[2]; wself = d.sumw[0] * d.invE; }
  const float ad0 = d.ad_[n*3], ad1 = d.ad_[n*3+1], ad2 = d.ad_[n*3+2];
  float sr0 = d.as_[n*3+0] + ad0 + wself*K0;  sr0 = sr0 >= 0.f ? sr0 : 0.2f*sr0;
  float sr1 = d.as_[n*3+1] + ad1 + wself*K1;  sr1 = sr1 >= 0.f ? sr1 : 0.2f*sr1;
  float sr2 = d.as_[n*3+2] + ad2 + wself*K2;  sr2 = sr2 >= 0.f ? sr2 : 0.2f*sr2;

  // pass A: raw scores + per-head max
  float mx0 = sr0, mx1 = sr1, mx2 = sr2;
  for (int i = t; i < deg; i += 256){
    int e = d.sorted[s0 + i];
    int s = d.src[e];
    float wv = hasW ? d.ew[e] : 0.f;
    float r0 = d.as_[s*3+0] + ad0 + wv*K0;  r0 = r0 >= 0.f ? r0 : 0.2f*r0;
    float r1 = d.as_[s*3+1] + ad1 + wv*K1;  r1 = r1 >= 0.f ? r1 : 0.2f*r1;
    float r2 = d.as_[s*3+2] + ad2 + wv*K2;  r2 = r2 >= 0.f ? r2 : 0.2f*r2;
    if (i < GCAP){ shs[i] = s; shx[i][0]=r0; shx[i][1]=r1; shx[i][2]=r2; }
    mx0 = fmaxf(mx0, r0); mx1 = fmaxf(mx1, r1); mx2 = fmaxf(mx2, r2);
  }
  for (int off = 32; off > 0; off >>= 1){
    mx0 = fmaxf(mx0, __shfl_down(mx0, off));
    mx1 = fmaxf(mx1, __shfl_down(mx1, off));
    mx2 = fmaxf(mx2, __shfl_down(mx2, off));
  }
  if (lane == 0){ redm[w][0]=mx0; redm[w][1]=mx1; redm[w][2]=mx2; }
  __syncthreads();
  const float M0 = fmaxf(fmaxf(redm[0][0],redm[1][0]), fmaxf(redm[2][0],redm[3][0]));
  const float M1 = fmaxf(fmaxf(redm[0][1],redm[1][1]), fmaxf(redm[2][1],redm[3][1]));
  const float M2 = fmaxf(fmaxf(redm[0][2],redm[1][2]), fmaxf(redm[2][2],redm[3][2]));

  // pass B: exp + sum
  float t0 = 0.f, t1 = 0.f, t2 = 0.f;
  for (int i = t; i < deg; i += 256){
    float r0, r1, r2;
    if (i < GCAP){ r0 = shx[i][0]; r1 = shx[i][1]; r2 = shx[i][2]; }
    else {
      int e = d.sorted[s0 + i]; int s = d.src[e];
      float wv = hasW ? d.ew[e] : 0.f;
      r0 = d.as_[s*3+0]+ad0+wv*K0; r0 = r0>=0.f?r0:0.2f*r0;
      r1 = d.as_[s*3+1]+ad1+wv*K1; r1 = r1>=0.f?r1:0.2f*r1;
      r2 = d.as_[s*3+2]+ad2+wv*K2; r2 = r2>=0.f?r2:0.2f*r2;
    }
    float e0 = expf(r0 - M0), e1 = expf(r1 - M1), e2 = expf(r2 - M2);
    if (i < GCAP){ shx[i][0]=e0; shx[i][1]=e1; shx[i][2]=e2; }
    t0 += e0; t1 += e1; t2 += e2;
  }
  for (int off = 32; off > 0; off >>= 1){
    t0 += __shfl_down(t0, off); t1 += __shfl_down(t1, off); t2 += __shfl_down(t2, off);
  }
  if (lane == 0){ reds[w][0]=t0; reds[w][1]=t1; reds[w][2]=t2; }
  __syncthreads();
  const float se0 = expf(sr0 - M0), se1 = expf(sr1 - M1), se2 = expf(sr2 - M2);
  const float i0 = 1.f / (reds[0][0]+reds[1][0]+reds[2][0]+reds[3][0] + se0 + 1e-16f);
  const float i1 = 1.f / (reds[0][1]+reds[1][1]+reds[2][1]+reds[3][1] + se1 + 1e-16f);
  const float i2 = 1.f / (reds[0][2]+reds[1][2]+reds[2][2]+reds[3][2] + se2 + 1e-16f);

  // pass C: alpha in original edge order
  for (int i = t; i < deg; i += 256){
    int e = d.sorted[s0 + i];
    float e0, e1, e2;
    if (i < GCAP){ e0 = shx[i][0]; e1 = shx[i][1]; e2 = shx[i][2]; }
    else {
      int s = d.src[e];
      float wv = hasW ? d.ew[e] : 0.f;
      float r0 = d.as_[s*3+0]+ad0+wv*K0; r0=r0>=0.f?r0:0.2f*r0;
      float r1 = d.as_[s*3+1]+ad1+wv*K1; r1=r1>=0.f?r1:0.2f*r1;
      float r2 = d.as_[s*3+2]+ad2+wv*K2; r2=r2>=0.f?r2:0.2f*r2;
      e0 = expf(r0-M0); e1 = expf(r1-M1); e2 = expf(r2-M2);
    }
    float* ap = d.alpha + (size_t)e * 3;
    ap[0] = e0 * i0; ap[1] = e1 * i1; ap[2] = e2 * i2;
  }
  if (t == 0){
    float* ap = d.alpha + (size_t)(d.E + n) * 3;
    ap[0] = se0 * i0; ap[1] = se1 * i1; ap[2] = se2 * i2;
  }

  // pass D: aggregation, edges split across the two thread-halves
  float f0, f1, f2;
  if (half == 0){
    const unsigned short* xn = d.xwb + (size_t)n * 384;
    f0 = bf2f(xn[c]) * se0; f1 = bf2f(xn[128+c]) * se1; f2 = bf2f(xn[256+c]) * se2;
  } else { f0 = f1 = f2 = 0.f; }
  for (int i = half; i < deg; i += 2){
    int s; float e0, e1, e2;
    if (i < GCAP){ s = shs[i]; e0 = shx[i][0]; e1 = shx[i][1]; e2 = shx[i][2]; }
    else {
      int e = d.sorted[s0 + i]; s = d.src[e];
      float wv = hasW ? d.ew[e] : 0.f;
      float r0 = d.as_[s*3+0]+ad0+wv*K0; r0=r0>=0.f?r0:0.2f*r0;
      float r1 = d.as_[s*3+1]+ad1+wv*K1; r1=r1>=0.f?r1:0.2f*r1;
      float r2 = d.as_[s*3+2]+ad2+wv*K2; r2=r2>=0.f?r2:0.2f*r2;
      e0 = expf(r0-M0); e1 = expf(r1-M1); e2 = expf(r2-M2);
    }
    const unsigned short* xs = d.xwb + (size_t)s * 384;
    f0 += bf2f(xs[c]) * e0; f1 += bf2f(xs[128+c]) * e1; f2 += bf2f(xs[256+c]) * e2;
  }
  if (half == 1){ shD[c][0] = f0; shD[c][1] = f1; shD[c][2] = f2; }
  __syncthreads();
  if (half == 0){
    f0 += shD[c][0]; f1 += shD[c][1]; f2 += shD[c][2];
    d.feat[(size_t)n*128 + c] = (f0*i0 + f1*i1 + f2*i2) * (1.f/3.f) + d.bias[c];
  }
}

// ===========================================================================
// Dispatch 5: BN-inline final GEMM, triple write.
// A = lrelu01(linV*scaleA+shiftA) -> bf16; B likewise from linH.
__global__ __launch_bounds__(256) void k_fin(
    const float* __restrict__ linV, const float* __restrict__ linH,
    const float* __restrict__ bnacc, const float* __restrict__ g, const float* __restrict__ bb,
    float* __restrict__ o0, float* __restrict__ o1, float* __restrict__ o2)
{
  __shared__ float sA[128], hA[128], sB[128], hB[128];
  const int t = threadIdx.x;
  if (t < 128){
    float mu  = bnacc[t] * (1.f/NV);
    float var = bnacc[128+t] * (1.f/NV) - mu*mu;
    float rs  = rsqrtf(var + 1e-5f);
    sA[t] = rs * g[t]; hA[t] = bb[t] - mu * rs * g[t];
  } else {
    int j = t - 128;
    float mu  = bnacc[256+j] * (1.f/NV);
    float var = bnacc[384+j] * (1.f/NV) - mu*mu;
    float rs  = rsqrtf(var + 1e-5f);
    sB[j] = rs * g[j]; hB[j] = bb[j] - mu * rs * g[j];
  }
  __syncthreads();

  const int lane = t & 63, w = t >> 6;
  const int wr = w >> 1, wc = w & 1;
  const int R  = blockIdx.y * 128 + wr * 64;
  const int Cb = blockIdx.x * 128 + wc * 64;
  const int r0 = lane & 15, kg = lane >> 4;

  const float* pa[4]; const float* pb[4];
  bool va[4], vb[4];
#pragma unroll
  for (int i = 0; i < 4; i++){
    int row = R + i * 16 + r0;
    va[i] = row < NV;
    pa[i] = linV + (size_t)(va[i] ? row : 0) * 128 + kg * 8;
    int col = Cb + i * 16 + r0;
    vb[i] = col < NH;
    pb[i] = linH + (size_t)(vb[i] ? col : 0) * 128 + kg * 8;
  }
  const bf16x8 Z8 = {0,0,0,0,0,0,0,0};
  f32x4 acc[4][4];
#pragma unroll
  for (int i = 0; i < 4; i++)
#pragma unroll
    for (int j = 0; j < 4; j++) acc[i][j] = (f32x4){0.f,0.f,0.f,0.f};

  for (int kk = 0; kk < 128; kk += 32){
    const int kb = kk + kg * 8;
    bf16x8 av[4], bv[4];
#pragma unroll
    for (int i = 0; i < 4; i++){
      bf16x8 fa, fb;
#pragma unroll
      for (int e = 0; e < 8; e++){
        float v1 = fmaf(pa[i][kk + e], sA[kb + e], hA[kb + e]);
        v1 = v1 >= 0.f ? v1 : 0.01f * v1;
        fa[e] = (short)f2bf(v1);
        float v2 = fmaf(pb[i][kk + e], sB[kb + e], hB[kb + e]);
        v2 = v2 >= 0.f ? v2 : 0.01f * v2;
        fb[e] = (short)f2bf(v2);
      }
      av[i] = va[i] ? fa : Z8;
      bv[i] = vb[i] ? fb : Z8;
    }
#pragma unroll
    for (int i = 0; i < 4; i++)
#pragma unroll
      for (int j = 0; j < 4; j++)
        acc[i][j] = __builtin_amdgcn_mfma_f32_16x16x32_bf16(av[i], bv[j], acc[i][j], 0, 0, 0);
  }

  const int cn = lane & 15, rq = (lane >> 4) * 4;
#pragma unroll
  for (int i = 0; i < 4; i++){
    int row0 = R + i * 16 + rq;
#pragma unroll
    for (int j = 0; j < 4; j++){
      int col = Cb + j * 16 + cn;
      if (col < NH){
#pragma unroll
        for (int r = 0; r < 4; r++){
          int row = row0 + r;
          if (row < NV){
            size_t idx = (size_t)row * NH + col;
            float v = acc[i][j][r];
            o0[idx] = v; o1[idx] = v; o2[idx] = v + v;
          }
        }
      }
    }
  }
}

// ===========================================================================
extern "C" void kernel_launch(void* const* d_in, const int* in_sizes, int n_in,
                              void* d_out, int out_size, void* d_ws, size_t ws_size,
                              hipStream_t stream)
{
  (void)in_sizes; (void)n_in; (void)out_size; (void)ws_size;
  const float* virus  = (const float*)d_in[0];
  const float* hostd  = (const float*)d_in[1];
  const float* coex   = (const float*)d_in[2];
  const float* vew    = (const float*)d_in[3];
  const float* hew    = (const float*)d_in[4];
  const float* vW     = (const float*)d_in[5];
  const float* v_as   = (const float*)d_in[6];
  const float* v_ad   = (const float*)d_in[7];
  const float* v_bias = (const float*)d_in[8];
  const float* v_line = (const float*)d_in[9];
  const float* v_atte = (const float*)d_in[10];
  const float* hW     = (const float*)d_in[11];
  const float* h_as   = (const float*)d_in[12];
  const float* h_ad   = (const float*)d_in[13];
  const float* h_bias = (const float*)d_in[14];
  const float* h_line = (const float*)d_in[15];
  const float* h_atte = (const float*)d_in[16];
  const float* vhW    = (const float*)d_in[17];
  const float* vh_as  = (const float*)d_in[18];
  const float* vh_ad  = (const float*)d_in[19];
  const float* vh_bias= (const float*)d_in[20];
  const float* hvW    = (const float*)d_in[21];
  const float* hv_as  = (const float*)d_in[22];
  const float* hv_ad  = (const float*)d_in[23];
  const float* hv_bias= (const float*)d_in[24];
  const float* linvW  = (const float*)d_in[25];
  const float* linhW  = (const float*)d_in[27];   // biases 26/28 cancel in BN
  const float* bng    = (const float*)d_in[29];
  const float* bnb    = (const float*)d_in[30];
  const int* vei  = (const int*)d_in[31];
  const int* hei  = (const int*)d_in[32];
  const int* cei  = (const int*)d_in[33];
  const int* ceit = (const int*)d_in[34];

  float* out = (float*)d_out;
  float* o0 = out;
  float* o1 = out + 36000000ll;
  float* o2 = out + 72000000ll;
  float* alpha_v  = out + 108000000ll;
  float* alpha_h  = alpha_v  + 618000;
  float* alpha_vh = alpha_h  + 618000;
  float* alpha_hv = alpha_vh + 101376;
  float* feat_v   = alpha_hv + 101376;
  float* feat_h   = feat_v   + 768000;
  float* feat_vh  = feat_h   + 768000;
  float* feat_hv  = feat_vh  + 131072;

  // ---------------- workspace carve-up ----------------
  char* wp = (char*)d_ws;
  auto alloc = [&](size_t b) -> void* { void* p = wp; wp += (b + 255) & ~(size_t)255; return p; };
  unsigned short* Avb  = (unsigned short*)alloc((size_t)NV*1024*2);
  unsigned short* Ahb  = (unsigned short*)alloc((size_t)NH*1024*2);
  unsigned short* Acb  = (unsigned short*)alloc((size_t)1024*1024*2);
  unsigned short* Actb = (unsigned short*)alloc((size_t)1024*1024*2);
  unsigned short* BtV  = (unsigned short*)alloc((size_t)512*1024*2);
  unsigned short* BtH  = (unsigned short*)alloc((size_t)512*1024*2);
  unsigned short* BtVH = (unsigned short*)alloc((size_t)384*1024*2);
  unsigned short* BtHV = (unsigned short*)alloc((size_t)384*1024*2);
  unsigned short* xwbV = (unsigned short*)alloc((size_t)NV*384*2);
  unsigned short* xwbH = (unsigned short*)alloc((size_t)NH*384*2);
  unsigned short* xwbC1= (unsigned short*)alloc((size_t)1024*384*2);
  unsigned short* xwbC2= (unsigned short*)alloc((size_t)1024*384*2);
  float* linV = (float*)alloc((size_t)NV*128*4);
  float* linH = (float*)alloc((size_t)NH*128*4);
  float* asV  = (float*)alloc(NV*3*4);   float* adV  = (float*)alloc(NV*3*4);
  float* asH  = (float*)alloc(NH*3*4);   float* adH  = (float*)alloc(NH*3*4);
  float* asC1 = (float*)alloc(1024*3*4); float* adC1 = (float*)alloc(1024*3*4);
  float* asC2 = (float*)alloc(1024*3*4); float* adC2 = (float*)alloc(1024*3*4);
  float* WasV = (float*)alloc(1024*3*4); float* WadV = (float*)alloc(1024*3*4);
  float* WasH = (float*)alloc(1024*3*4); float* WadH = (float*)alloc(1024*3*4);
  float* WasC1= (float*)alloc(1024*3*4); float* WadC1= (float*)alloc(1024*3*4);
  float* WasC2= (float*)alloc(1024*3*4); float* WadC2= (float*)alloc(1024*3*4);
  int* startsV  = (int*)alloc((NV+1)*4);  int* sortedV  = (int*)alloc((size_t)EV*4);
  int* startsH  = (int*)alloc((NH+1)*4);  int* sortedH  = (int*)alloc((size_t)EH*4);
  int* startsC1 = (int*)alloc(1025*4);    int* sortedC1 = (int*)alloc((size_t)EC*4);
  int* startsC2 = (int*)alloc(1025*4);    int* sortedC2 = (int*)alloc((size_t)EC*4);
  float* Kbuf  = (float*)alloc(256);
  // zero-init region
  char* z0 = wp;
  int* cntV  = (int*)alloc(NV*4);   int* curV  = (int*)alloc(NV*4);
  int* cntH  = (int*)alloc(NH*4);   int* curH  = (int*)alloc(NH*4);
  int* cntC1 = (int*)alloc(1024*4); int* curC1 = (int*)alloc(1024*4);
  int* cntC2 = (int*)alloc(1024*4); int* curC2 = (int*)alloc(1024*4);
  float* sums  = (float*)alloc(256);
  float* bnacc = (float*)alloc(512*4);
  hipMemsetAsync(z0, 0, (size_t)(wp - z0), stream);

  const int* vsrc = vei,  *vdst = vei  + EV;
  const int* hsrc = hei,  *hdst = hei  + EH;
  const int* c1src= ceit, *c1dst= ceit + EC;   // vh GAT: transposed indices
  const int* c2src= cei,  *c2dst= cei  + EC;   // hv GAT: plain indices

  // 1: pack + transpose + W·a scalars + histogram + ew sums + Kbuf
  k_prep<<<17852, 256, 0, stream>>>(virus, hostd, coex,
      vW, linvW, hW, linhW, vhW, hvW,
      v_as, v_ad, h_as, h_ad, vh_as, vh_ad, hv_as, hv_ad,
      vew, hew, v_line, v_atte, h_line, h_atte,
      vdst, hdst, c1dst, c2dst,
      Avb, Ahb, Acb, Actb, BtV, BtH, BtVH, BtHV,
      WasV, WadV, WasH, WadH, WasC1, WadC1, WasC2, WadC2,
      sums, Kbuf, cntV, cntH, cntC1, cntC2);
  // 2: scans + node dots
  k_nd<<<13060, 256, 0, stream>>>(cntV, startsV, cntH, startsH, cntC1, startsC1, cntC2, startsC2,
      virus, hostd, coex,
      WasV, WadV, WasH, WadH, WasC1, WadC1, WasC2, WadC2,
      asV, adV, asH, adH, asC1, adC1, asC2, adC2);
  // 3: xw GEMMs + CSR scatter
  k_sg<<<2243, 256, 0, stream>>>(Avb, BtV, xwbV, linV, Ahb, BtH, xwbH, linH,
      Acb, BtVH, xwbC1, Actb, BtHV, xwbC2,
      vdst, hdst, c1dst, c2dst,
      startsV, startsH, startsC1, startsC2,
      curV, curH, curC1, curC2,
      sortedV, sortedH, sortedC1, sortedC2);
  // 4: fused GAT ×4 + BN stats
  {
    GatDesc dv = { xwbV,  vsrc,  sortedV,  startsV,  asV,  adV,  Kbuf,   vew, &sums[0], v_bias,
                   alpha_v,  feat_v,  EV, 1.f/EV };
    GatDesc dh = { xwbH,  hsrc,  sortedH,  startsH,  asH,  adH,  Kbuf+3, hew, &sums[1], h_bias,
                   alpha_h,  feat_h,  EH, 1.f/EH };
    GatDesc dc1= { xwbC1, c1src, sortedC1, startsC1, asC1, adC1, nullptr, nullptr, nullptr, vh_bias,
                   alpha_vh, feat_vh, EC, 0.f };
    GatDesc dc2= { xwbC2, c2src, sortedC2, startsC2, asC2, adC2, nullptr, nullptr, nullptr, hv_bias,
                   alpha_hv, feat_hv, EC, 0.f };
    k_gatbn<<<14424, 256, 0, stream>>>(dv, dh, dc1, dc2, linV, linH, bnacc);
  }
  // 5: BN-inline final GEMM, triple write
  k_fin<<<dim3(47,47), 256, 0, stream>>>(linV, linH, bnacc, bng, bnb, o0, o1, o2);
}